// Round 1
// baseline (555.762 us; speedup 1.0000x reference)
//
#include <hip/hip_runtime.h>
#include <hip/hip_bf16.h>

#define NB 4
#define SL 2048
#define EM 768
#define NHD 12
#define DHD 64
#define MLPD 3072
#define NHASH 4
#define NBS 48        // NB*NHD
#define NPOS 98304    // NBS*SL
#define MLROWS 8192   // NB*SL

typedef __attribute__((ext_vector_type(8))) short short8;
typedef __attribute__((ext_vector_type(8))) _Float16 f16x8;
typedef __attribute__((ext_vector_type(4))) float f32x4;

__device__ __forceinline__ unsigned short f2bf(float x){
  unsigned u = __float_as_uint(x);
  u += 0x7fffu + ((u>>16)&1u);
  return (unsigned short)(u>>16);
}
__device__ __forceinline__ float bf2f(unsigned short s){
  return __uint_as_float(((unsigned)s)<<16);
}
__device__ __forceinline__ int sw128(int row, int colbyte){ return row*128 + (colbyte ^ ((row&7)<<4)); }
__device__ __forceinline__ int sw256(int row, int colbyte){ return row*256 + (colbyte ^ ((row&7)<<4)); }

// ---------------- weight prep ----------------
__global__ __launch_bounds__(256) void wsplit_kernel(const float* __restrict__ w,
    _Float16* __restrict__ wh, _Float16* __restrict__ wl, int n){
  int i = blockIdx.x*256 + threadIdx.x;
  if (i < n){
    float x = w[i]*1024.0f;           // pre-scale keeps lo part out of fp16 denorms
    _Float16 h = (_Float16)x;
    wh[i] = h;
    wl[i] = (_Float16)((x - (float)h)*2048.0f);
  }
}
__global__ __launch_bounds__(256) void tobf_kernel(const float* __restrict__ w,
    unsigned short* __restrict__ o, int n){
  int i = blockIdx.x*256 + threadIdx.x;
  if (i < n) o[i] = f2bf(w[i]);
}

// ---------------- layernorm ----------------
// MODE 0: write fp16 hi/lo split (for fp16x2 QKV GEMM). MODE 1: write bf16.
template<int MODE>
__global__ __launch_bounds__(256) void ln_kernel(const float* __restrict__ x,
    const float* __restrict__ g, const float* __restrict__ bb,
    _Float16* __restrict__ hh, _Float16* __restrict__ hl, unsigned short* __restrict__ ob){
  int row = blockIdx.x; int tid = threadIdx.x;
  const float* xr = x + (size_t)row*EM;
  float v0 = xr[tid], v1 = xr[tid+256], v2 = xr[tid+512];
  __shared__ float sb[8];
  float s = v0+v1+v2;
  #pragma unroll
  for (int off=32; off; off>>=1) s += __shfl_down(s, off);
  if ((tid&63)==0) sb[tid>>6] = s;
  __syncthreads();
  float mean = (sb[0]+sb[1]+sb[2]+sb[3]) * (1.0f/768.0f);
  float d0=v0-mean, d1=v1-mean, d2=v2-mean;
  float q_ = d0*d0 + d1*d1 + d2*d2;
  #pragma unroll
  for (int off=32; off; off>>=1) q_ += __shfl_down(q_, off);
  __syncthreads();
  if ((tid&63)==0) sb[tid>>6] = q_;
  __syncthreads();
  float var = (sb[0]+sb[1]+sb[2]+sb[3]) * (1.0f/768.0f);
  float rs = rsqrtf(var + 1e-6f);
  float dv[3] = {d0,d1,d2};
  #pragma unroll
  for (int e=0;e<3;e++){
    int cc = tid + e*256;
    float val = dv[e]*rs*g[cc] + bb[cc];
    size_t oi = (size_t)row*EM + cc;
    if (MODE==0){
      _Float16 h = (_Float16)val;
      hh[oi] = h;
      hl[oi] = (_Float16)((val - (float)h)*2048.0f);
    } else {
      ob[oi] = f2bf(val);
    }
  }
}

// ---------------- QKV GEMM, fp16x2 split (fp32-class precision) ----------------
__global__ __launch_bounds__(256) void qkv_gemm(const _Float16* __restrict__ Ah, const _Float16* __restrict__ Al,
    const _Float16* __restrict__ Wh, const _Float16* __restrict__ Wl, const float* __restrict__ bias,
    float* __restrict__ qo, float* __restrict__ ko, unsigned short* __restrict__ vo){
  __shared__ char sAh[16384], sAl[16384], sBh[16384], sBl[16384];
  const int tid=threadIdx.x, l=tid&63, w=tid>>6, wm=w>>1, wn=w&1;
  const int m0 = blockIdx.x*128, n0 = blockIdx.y*128;
  f32x4 a1[4][4] = {}; f32x4 a2[4][4] = {};
  for (int k0=0;k0<EM;k0+=64){
    __syncthreads();
    #pragma unroll
    for (int i=0;i<4;i++){
      int s = tid + i*256, row = s>>3, sl = s&7;
      int lo = sw128(row, sl*16);
      size_t ga = (size_t)(m0+row)*EM + k0 + sl*8;
      size_t gb = (size_t)(n0+row)*EM + k0 + sl*8;
      *(uint4*)(sAh+lo) = *(const uint4*)(Ah+ga);
      *(uint4*)(sAl+lo) = *(const uint4*)(Al+ga);
      *(uint4*)(sBh+lo) = *(const uint4*)(Wh+gb);
      *(uint4*)(sBl+lo) = *(const uint4*)(Wl+gb);
    }
    __syncthreads();
    #pragma unroll
    for (int ks=0;ks<2;ks++){
      int cb = ks*64 + ((l>>4)<<4);
      f16x8 ah[4], al_[4];
      #pragma unroll
      for (int i=0;i<4;i++){
        int off = sw128(wm*64+i*16+(l&15), cb);
        ah[i]  = *(const f16x8*)(sAh+off);
        al_[i] = *(const f16x8*)(sAl+off);
      }
      #pragma unroll
      for (int j=0;j<4;j++){
        int off = sw128(wn*64+j*16+(l&15), cb);
        f16x8 bh = *(const f16x8*)(sBh+off);
        f16x8 bl = *(const f16x8*)(sBl+off);
        #pragma unroll
        for (int i=0;i<4;i++){
          a1[i][j] = __builtin_amdgcn_mfma_f32_16x16x32_f16(ah[i],  bh, a1[i][j],0,0,0);
          a2[i][j] = __builtin_amdgcn_mfma_f32_16x16x32_f16(ah[i],  bl, a2[i][j],0,0,0);
          a2[i][j] = __builtin_amdgcn_mfma_f32_16x16x32_f16(al_[i], bh, a2[i][j],0,0,0);
        }
      }
    }
  }
  #pragma unroll
  for (int i=0;i<4;i++)
  #pragma unroll
  for (int j=0;j<4;j++)
  #pragma unroll
  for (int rr=0;rr<4;rr++){
    int gm = m0 + wm*64 + i*16 + (l>>4)*4 + rr;
    int gn = n0 + wn*64 + j*16 + (l&15);
    float v = (a1[i][j][rr] + a2[i][j][rr]*4.8828125e-4f)*9.765625e-4f + bias[gn];
    int sec = gn/768; int hh = (gn%768)>>6; int d = gn&63;
    int b = gm>>11; int ll = gm&2047;
    size_t idx = (((size_t)(b*NHD+hh))*SL + ll)*DHD + d;
    if (sec==0)      qo[idx] = v*0.125f;   // q pre-scaled by DH^-0.5
    else if (sec==1) ko[idx] = v;
    else             vo[idx] = f2bf(v);
  }
}

// ---------------- squared norms + global max ----------------
__global__ __launch_bounds__(256) void sqmax_kernel(const float* __restrict__ q, const float* __restrict__ k,
    float* __restrict__ qsq, float* __restrict__ ksq, unsigned* __restrict__ scal){
  bool isq = blockIdx.x < 512;
  const float* src = isq ? q : k;
  float* dst = isq ? qsq : ksq;
  int wg = ((blockIdx.x & 511)<<2) + (threadIdx.x>>6);
  int lane = threadIdx.x & 63;
  float mx = 0.f;
  for (int pos = wg; pos < NPOS; pos += 2048){
    float val = src[(size_t)pos*DHD + lane];
    float sq = val*val;
    #pragma unroll
    for (int off=32; off; off>>=1) sq += __shfl_xor(sq, off);
    if (lane==0) dst[pos] = sq;
    mx = fmaxf(mx, sq);
  }
  __shared__ float sm[4];
  if (lane==0) sm[threadIdx.x>>6] = mx;
  __syncthreads();
  if (threadIdx.x==0){
    float m2 = fmaxf(fmaxf(sm[0],sm[1]), fmaxf(sm[2],sm[3]));
    atomicMax(scal + (isq?0:1), __float_as_uint(m2));   // positives: uint order == float order
  }
}

// ---------------- E2LSH hash values ----------------
__global__ __launch_bounds__(256) void hash_kernel(const float* __restrict__ q, const float* __restrict__ k,
    const float* __restrict__ qsq, const float* __restrict__ ksq, const unsigned* __restrict__ scal,
    const float* __restrict__ alpha, const float* __restrict__ beta,
    float* __restrict__ hq, float* __restrict__ hk){
  __shared__ __align__(16) float sal[264];
  __shared__ __align__(16) float sbe[4];
  for (int i=threadIdx.x; i<264; i+=256) sal[i] = alpha[i];
  if (threadIdx.x<4) sbe[threadIdx.x] = beta[threadIdx.x];
  __syncthreads();
  int gw = blockIdx.x*4 + (threadIdx.x>>6);
  int lane = threadIdx.x & 63;
  bool isq = gw < NPOS;
  int pos = isq ? gw : gw - NPOS;
  const float* src = isq ? q : k;
  const float* sqp = isq ? qsq : ksq;
  float m_tot = __uint_as_float(scal[0]) + __uint_as_float(scal[1]);
  float val = src[(size_t)pos*DHD + lane];
  float4 a = *(const float4*)&sal[lane*4];   // alpha[d][0..3]
  float h0 = val*a.x, h1 = val*a.y, h2 = val*a.z, h3 = val*a.w;
  #pragma unroll
  for (int off=32; off; off>>=1){
    h0 += __shfl_xor(h0,off); h1 += __shfl_xor(h1,off);
    h2 += __shfl_xor(h2,off); h3 += __shfl_xor(h3,off);
  }
  if (lane==0){
    float ext = sqrtf(fmaxf(m_tot - sqp[pos], 0.f));
    const float* ae = &sal[(isq?64:65)*4];   // XBOX+ row: 64 for Q, 65 for K
    float* out = isq ? hq : hk;
    out[0*NPOS + pos] = h0 + ext*ae[0] + sbe[0];
    out[1*NPOS + pos] = h1 + ext*ae[1] + sbe[1];
    out[2*NPOS + pos] = h2 + ext*ae[2] + sbe[2];
    out[3*NPOS + pos] = h3 + ext*ae[3] + sbe[3];
  }
}

// ---------------- bitonic argsort of 2048 keys ----------------
__global__ __launch_bounds__(1024) void sort_kernel(const float* __restrict__ hq, const float* __restrict__ hk,
    int* __restrict__ qpos, int* __restrict__ kpos){
  __shared__ float sv[2048];
  __shared__ int si[2048];
  int bid = blockIdx.x;
  bool isq = bid < 192;
  int row = isq ? bid : bid-192;
  const float* h = (isq?hq:hk) + (size_t)row*SL;
  int* op = (isq?qpos:kpos) + (size_t)row*SL;
  for (int i=threadIdx.x; i<SL; i+=1024){ sv[i]=h[i]; si[i]=i; }
  __syncthreads();
  for (int kk=2; kk<=SL; kk<<=1){
    for (int j=kk>>1; j>0; j>>=1){
      int t = threadIdx.x;
      int i1 = ((t & ~(j-1))<<1) | (t & (j-1));
      int i2 = i1 | j;
      bool up = (i1 & kk)==0;
      float a = sv[i1], b = sv[i2];
      int ia = si[i1], ib = si[i2];
      if ((a>b)==up){ sv[i1]=b; sv[i2]=a; si[i1]=ib; si[i2]=ia; }
      __syncthreads();
    }
  }
  for (int i=threadIdx.x; i<SL; i+=1024) op[i]=si[i];
}

// ---------------- within-cluster attention ----------------
__global__ __launch_bounds__(256) void attn_kernel(const float* __restrict__ q, const float* __restrict__ k,
    const unsigned short* __restrict__ v, const int* __restrict__ qpos, const int* __restrict__ kpos,
    unsigned short* __restrict__ oh, float* __restrict__ lseh){
  __shared__ __align__(16) char smem[50176];
  char* qs  = smem;               // [128][64] bf16 (swizzled), later reused as P rows 0..63
  char* ks_ = smem + 16384;       // [128][64] bf16, later reused as P rows 64..127
  char* P   = smem;               // [128][128] bf16 (swizzled 256B rows)
  char* vt  = smem + 32768;       // [64][128] bf16 V^T (swizzled 256B rows)
  int* idxq = (int*)(smem + 49152);
  int* idxk = (int*)(smem + 49664);

  const int tid = threadIdx.x, l = tid&63, w = tid>>6;
  const int bid = blockIdx.x;
  const int c = bid&15, rb = bid>>4, bs = rb%NBS, r = rb/NBS;
  const size_t rowbase = ((size_t)r*NBS + bs)*SL;
  if (tid < 128) idxq[tid] = qpos[rowbase + c*128 + tid];
  else           idxk[tid-128] = kpos[rowbase + c*128 + (tid-128)];
  __syncthreads();

  const float* qb = q + (size_t)bs*SL*DHD;
  const float* kb = k + (size_t)bs*SL*DHD;
  const unsigned short* vb = v + (size_t)bs*SL*DHD;
  #pragma unroll
  for (int p=0;p<8;p++){
    int row = p*16 + (tid>>4); int ch = tid&15;
    {
      int orig = idxq[row];
      float4 f = *(const float4*)(qb + (size_t)orig*DHD + ch*4);
      uint2 pk; pk.x = (unsigned)f2bf(f.x) | ((unsigned)f2bf(f.y)<<16);
      pk.y = (unsigned)f2bf(f.z) | ((unsigned)f2bf(f.w)<<16);
      *(uint2*)(qs + sw128(row, ch*8)) = pk;
    }
    {
      int orig = idxk[row];
      float4 f = *(const float4*)(kb + (size_t)orig*DHD + ch*4);
      uint2 pk; pk.x = (unsigned)f2bf(f.x) | ((unsigned)f2bf(f.y)<<16);
      pk.y = (unsigned)f2bf(f.z) | ((unsigned)f2bf(f.w)<<16);
      *(uint2*)(ks_ + sw128(row, ch*8)) = pk;
    }
    {
      int orig = idxk[row];
      ushort4 vv = *(const ushort4*)(vb + (size_t)orig*DHD + ch*4);
      unsigned short arr[4] = {vv.x, vv.y, vv.z, vv.w};
      #pragma unroll
      for (int ii=0;ii<4;ii++){
        int d = ch*4+ii;
        *(unsigned short*)(vt + sw256(d, row*2)) = arr[ii];   // transpose on the fly
      }
    }
  }
  __syncthreads();

  // S = q_s @ k_s^T  (wave w owns rows w*32..w*32+31)
  f32x4 sc[2][8] = {};
  #pragma unroll
  for (int ks=0;ks<2;ks++){
    int cb = ks*64 + ((l>>4)<<4);
    short8 aq[2];
    aq[0] = *(const short8*)(qs + sw128(w*32 +      (l&15), cb));
    aq[1] = *(const short8*)(qs + sw128(w*32 + 16 + (l&15), cb));
    #pragma unroll
    for (int nj=0;nj<8;nj++){
      short8 bk = *(const short8*)(ks_ + sw128(nj*16+(l&15), cb));
      sc[0][nj] = __builtin_amdgcn_mfma_f32_16x16x32_bf16(aq[0], bk, sc[0][nj],0,0,0);
      sc[1][nj] = __builtin_amdgcn_mfma_f32_16x16x32_bf16(aq[1], bk, sc[1][nj],0,0,0);
    }
  }
  __syncthreads();   // all q_s/k_s reads done before P overwrites the region

  // row-wise softmax (16-lane groups hold a row), normalized P + lse scatter
  #pragma unroll
  for (int mi=0;mi<2;mi++)
  #pragma unroll
  for (int rr=0;rr<4;rr++){
    float mx = -3.0e38f;
    #pragma unroll
    for (int nj=0;nj<8;nj++) mx = fmaxf(mx, sc[mi][nj][rr]);
    #pragma unroll
    for (int off=1; off<16; off<<=1) mx = fmaxf(mx, __shfl_xor(mx, off));
    float s = 0.f;
    #pragma unroll
    for (int nj=0;nj<8;nj++){ float p_ = expf(sc[mi][nj][rr]-mx); sc[mi][nj][rr]=p_; s += p_; }
    #pragma unroll
    for (int off=1; off<16; off<<=1) s += __shfl_xor(s, off);
    float inv = 1.0f/s;
    int row = w*32 + mi*16 + (l>>4)*4 + rr;
    #pragma unroll
    for (int nj=0;nj<8;nj++){
      int col = nj*16 + (l&15);
      *(unsigned short*)(P + sw256(row, col*2)) = f2bf(sc[mi][nj][rr]*inv);
    }
    if ((l&15)==0){
      int orig = idxq[row];
      lseh[rowbase + orig] = mx + logf(s);
    }
  }
  __syncthreads();

  // O = P @ V
  f32x4 o[2][4] = {};
  #pragma unroll
  for (int ks=0;ks<4;ks++){
    int cb = ks*64 + ((l>>4)<<4);
    short8 pa[2];
    pa[0] = *(const short8*)(P + sw256(w*32 +      (l&15), cb));
    pa[1] = *(const short8*)(P + sw256(w*32 + 16 + (l&15), cb));
    #pragma unroll
    for (int nd=0;nd<4;nd++){
      short8 bv = *(const short8*)(vt + sw256(nd*16+(l&15), cb));
      o[0][nd] = __builtin_amdgcn_mfma_f32_16x16x32_bf16(pa[0], bv, o[0][nd],0,0,0);
      o[1][nd] = __builtin_amdgcn_mfma_f32_16x16x32_bf16(pa[1], bv, o[1][nd],0,0,0);
    }
  }
  #pragma unroll
  for (int mi=0;mi<2;mi++)
  #pragma unroll
  for (int nd=0;nd<4;nd++)
  #pragma unroll
  for (int rr=0;rr<4;rr++){
    int row = w*32 + mi*16 + (l>>4)*4 + rr;
    int orig = idxq[row];
    oh[(rowbase + orig)*DHD + nd*16 + (l&15)] = f2bf(o[mi][nd][rr]);
  }
}

// ---------------- merge hash rounds ----------------
__global__ __launch_bounds__(256) void merge_kernel(const unsigned short* __restrict__ oh,
    const float* __restrict__ lseh, unsigned short* __restrict__ attnb){
  int idx = blockIdx.x*256 + threadIdx.x;
  int d = idx&63; int pos = idx>>6; int ll = pos & (SL-1); int bs = pos >> 11;
  float l0 = lseh[0*NPOS+pos], l1 = lseh[1*NPOS+pos], l2 = lseh[2*NPOS+pos], l3 = lseh[3*NPOS+pos];
  float mx = fmaxf(fmaxf(l0,l1),fmaxf(l2,l3));
  float w0 = expf(l0-mx), w1 = expf(l1-mx), w2 = expf(l2-mx), w3 = expf(l3-mx);
  float inv = 1.0f/(w0+w1+w2+w3);
  float acc = (w0*bf2f(oh[((size_t)0*NPOS+pos)*DHD+d]) +
               w1*bf2f(oh[((size_t)1*NPOS+pos)*DHD+d]) +
               w2*bf2f(oh[((size_t)2*NPOS+pos)*DHD+d]) +
               w3*bf2f(oh[((size_t)3*NPOS+pos)*DHD+d]))*inv;
  int b = bs/NHD, hh = bs%NHD;
  attnb[((size_t)(b*SL)+ll)*EM + hh*DHD + d] = f2bf(acc);
}

// ---------------- generic bf16 NT GEMM ----------------
// EPI 0: outf = acc + bias + res (fp32).  EPI 1: outb = bf16(gelu(acc + bias)).
template<int EPI>
__global__ __launch_bounds__(256) void gemm_bf16(const unsigned short* __restrict__ A,
    const unsigned short* __restrict__ Bw, const float* __restrict__ bias,
    const float* __restrict__ res, float* __restrict__ outf, unsigned short* __restrict__ outb,
    int M, int N, int K){
  __shared__ char sA[16384], sB[16384];
  const int tid=threadIdx.x, l=tid&63, w=tid>>6, wm=w>>1, wn=w&1;
  const int m0 = blockIdx.x*128, n0 = blockIdx.y*128;
  f32x4 acc[4][4] = {};
  for (int k0=0;k0<K;k0+=64){
    __syncthreads();
    #pragma unroll
    for (int i=0;i<4;i++){
      int s = tid + i*256, row = s>>3, sl = s&7;
      *(uint4*)(sA + sw128(row, sl*16)) = *(const uint4*)(A  + (size_t)(m0+row)*K + k0 + sl*8);
      *(uint4*)(sB + sw128(row, sl*16)) = *(const uint4*)(Bw + (size_t)(n0+row)*K + k0 + sl*8);
    }
    __syncthreads();
    #pragma unroll
    for (int ks=0;ks<2;ks++){
      int cb = ks*64 + ((l>>4)<<4);
      short8 af[4], bfr[4];
      #pragma unroll
      for (int i=0;i<4;i++){
        af[i]  = *(const short8*)(sA + sw128(wm*64+i*16+(l&15), cb));
        bfr[i] = *(const short8*)(sB + sw128(wn*64+i*16+(l&15), cb));
      }
      #pragma unroll
      for (int i=0;i<4;i++)
      #pragma unroll
      for (int j=0;j<4;j++)
        acc[i][j] = __builtin_amdgcn_mfma_f32_16x16x32_bf16(af[i], bfr[j], acc[i][j],0,0,0);
    }
  }
  #pragma unroll
  for (int i=0;i<4;i++)
  #pragma unroll
  for (int j=0;j<4;j++)
  #pragma unroll
  for (int rr=0;rr<4;rr++){
    int gm = m0 + wm*64 + i*16 + (l>>4)*4 + rr;
    int gn = n0 + wn*64 + j*16 + (l&15);
    float v = acc[i][j][rr] + bias[gn];
    size_t oidx = (size_t)gm*N + gn;
    if (EPI==0) outf[oidx] = v + res[oidx];
    else { float ge = 0.5f*v*(1.0f + erff(v*0.70710678118654752f)); outb[oidx] = f2bf(ge); }
  }
}

extern "C" void kernel_launch(void* const* d_in, const int* in_sizes, int n_in,
                              void* d_out, int out_size, void* d_ws, size_t ws_size,
                              hipStream_t stream){
  const float* x    = (const float*)d_in[0];
  const float* ln1g = (const float*)d_in[1];
  const float* ln1b = (const float*)d_in[2];
  const float* wqkv = (const float*)d_in[3];
  const float* bqkv = (const float*)d_in[4];
  const float* wout = (const float*)d_in[5];
  const float* bout = (const float*)d_in[6];
  const float* ln2g = (const float*)d_in[7];
  const float* ln2b = (const float*)d_in[8];
  const float* w1   = (const float*)d_in[9];
  const float* b1   = (const float*)d_in[10];
  const float* w2   = (const float*)d_in[11];
  const float* b2   = (const float*)d_in[12];
  const float* alpha= (const float*)d_in[13];
  const float* beta = (const float*)d_in[14];
  float* out = (float*)d_out;

  char* ws = (char*)d_ws;
  size_t off = 0;
  auto A = [&](size_t n)->char*{ char* p = ws+off; off += (n+255)&~(size_t)255; return p; };
  _Float16* h_hi = (_Float16*)A(12582912);
  _Float16* h_lo = (_Float16*)A(12582912);
  _Float16* wq_h = (_Float16*)A(3538944);
  _Float16* wq_l = (_Float16*)A(3538944);
  unsigned short* wo_b = (unsigned short*)A(1179648);
  unsigned short* w1_b = (unsigned short*)A(4718592);
  unsigned short* w2_b = (unsigned short*)A(4718592);
  float* qbuf = (float*)A(25165824);
  float* kbuf = (float*)A(25165824);
  unsigned short* vbuf = (unsigned short*)A(12582912);
  float* qsq = (float*)A(393216);
  float* ksq = (float*)A(393216);
  unsigned* scal = (unsigned*)A(256);
  float* hq = (float*)A(1572864);
  float* hk = (float*)A(1572864);
  int* qpos = (int*)A(1572864);
  int* kpos = (int*)A(1572864);
  unsigned short* oh = (unsigned short*)A(50331648);
  float* lseh = (float*)A(1572864);
  // aliases (lifetime-disjoint)
  unsigned short* attnb = vbuf;                 // v dead after attn_kernel
  float* x2 = (float*)oh;                       // oh dead after merge_kernel
  unsigned short* yb = (unsigned short*)h_hi;   // h dead after qkv_gemm
  unsigned short* ub = (unsigned short*)qbuf;   // q,k dead after attn_kernel (contiguous 48MB span)

  hipMemsetAsync(scal, 0, 8, stream);
  { int n = 2304*768; wsplit_kernel<<<(n+255)/256, 256, 0, stream>>>(wqkv, wq_h, wq_l, n); }
  { int n = 768*768;  tobf_kernel<<<(n+255)/256, 256, 0, stream>>>(wout, wo_b, n); }
  { int n = 3072*768; tobf_kernel<<<(n+255)/256, 256, 0, stream>>>(w1, w1_b, n); }
  { int n = 768*3072; tobf_kernel<<<(n+255)/256, 256, 0, stream>>>(w2, w2_b, n); }
  ln_kernel<0><<<MLROWS, 256, 0, stream>>>(x, ln1g, ln1b, h_hi, h_lo, nullptr);
  qkv_gemm<<<dim3(64,18), 256, 0, stream>>>(h_hi, h_lo, wq_h, wq_l, bqkv, qbuf, kbuf, vbuf);
  sqmax_kernel<<<1024, 256, 0, stream>>>(qbuf, kbuf, qsq, ksq, scal);
  hash_kernel<<<49152, 256, 0, stream>>>(qbuf, kbuf, qsq, ksq, scal, alpha, beta, hq, hk);
  sort_kernel<<<384, 1024, 0, stream>>>(hq, hk, qpos, kpos);
  attn_kernel<<<3072, 256, 0, stream>>>(qbuf, kbuf, vbuf, qpos, kpos, oh, lseh);
  merge_kernel<<<24576, 256, 0, stream>>>(oh, lseh, attnb);
  gemm_bf16<0><<<dim3(64,6),  256, 0, stream>>>(attnb, wo_b, bout, x,  x2,  nullptr, MLROWS, 768, 768);
  ln_kernel<1><<<MLROWS, 256, 0, stream>>>(x2, ln2g, ln2b, nullptr, nullptr, yb);
  gemm_bf16<1><<<dim3(64,24), 256, 0, stream>>>(yb, w1_b, b1, nullptr, nullptr, ub, MLROWS, 3072, 768);
  gemm_bf16<0><<<dim3(64,6),  256, 0, stream>>>(ub, w2_b, b2, x2, out, nullptr, MLROWS, 768, 3072);
}

// Round 2
// 497.485 us; speedup vs baseline: 1.1171x; 1.1171x over previous
//
#include <hip/hip_runtime.h>
#include <hip/hip_bf16.h>

#define NB 4
#define SL 2048
#define EM 768
#define NHD 12
#define DHD 64
#define MLPD 3072
#define NHASH 4
#define NBS 48        // NB*NHD
#define NPOS 98304    // NBS*SL
#define MLROWS 8192   // NB*SL

typedef __attribute__((ext_vector_type(8))) short short8;
typedef __attribute__((ext_vector_type(8))) _Float16 f16x8;
typedef __attribute__((ext_vector_type(4))) float f32x4;

__device__ __forceinline__ unsigned short f2bf(float x){
  unsigned u = __float_as_uint(x);
  u += 0x7fffu + ((u>>16)&1u);
  return (unsigned short)(u>>16);
}
__device__ __forceinline__ float bf2f(unsigned short s){
  return __uint_as_float(((unsigned)s)<<16);
}
__device__ __forceinline__ int sw128(int row, int colbyte){ return row*128 + (colbyte ^ ((row&7)<<4)); }
__device__ __forceinline__ int sw256(int row, int colbyte){ return row*256 + (colbyte ^ ((row&7)<<4)); }

// async global->LDS, 16B per lane; LDS dest = wave-uniform base + lane*16
__device__ __forceinline__ void gll16(const void* g, const void* l){
  __builtin_amdgcn_global_load_lds(
      (const __attribute__((address_space(1))) void*)(uintptr_t)g,
      (__attribute__((address_space(3))) void*)(unsigned int)(uintptr_t)l,
      16, 0, 0);
}

// ---------------- weight prep ----------------
__global__ __launch_bounds__(256) void wsplit_kernel(const float* __restrict__ w,
    _Float16* __restrict__ wh, _Float16* __restrict__ wl, int n){
  int i = blockIdx.x*256 + threadIdx.x;
  if (i < n){
    float x = w[i]*1024.0f;           // pre-scale keeps lo part out of fp16 denorms
    _Float16 h = (_Float16)x;
    wh[i] = h;
    wl[i] = (_Float16)((x - (float)h)*2048.0f);
  }
}
__global__ __launch_bounds__(256) void tobf_kernel(const float* __restrict__ w,
    unsigned short* __restrict__ o, int n){
  int i = blockIdx.x*256 + threadIdx.x;
  if (i < n) o[i] = f2bf(w[i]);
}

// ---------------- layernorm ----------------
// MODE 0: write fp16 hi/lo split (for fp16x2 QKV GEMM). MODE 1: write bf16.
template<int MODE>
__global__ __launch_bounds__(256) void ln_kernel(const float* __restrict__ x,
    const float* __restrict__ g, const float* __restrict__ bb,
    _Float16* __restrict__ hh, _Float16* __restrict__ hl, unsigned short* __restrict__ ob){
  int row = blockIdx.x; int tid = threadIdx.x;
  const float* xr = x + (size_t)row*EM;
  float v0 = xr[tid], v1 = xr[tid+256], v2 = xr[tid+512];
  __shared__ float sb[8];
  float s = v0+v1+v2;
  #pragma unroll
  for (int off=32; off; off>>=1) s += __shfl_down(s, off);
  if ((tid&63)==0) sb[tid>>6] = s;
  __syncthreads();
  float mean = (sb[0]+sb[1]+sb[2]+sb[3]) * (1.0f/768.0f);
  float d0=v0-mean, d1=v1-mean, d2=v2-mean;
  float q_ = d0*d0 + d1*d1 + d2*d2;
  #pragma unroll
  for (int off=32; off; off>>=1) q_ += __shfl_down(q_, off);
  __syncthreads();
  if ((tid&63)==0) sb[tid>>6] = q_;
  __syncthreads();
  float var = (sb[0]+sb[1]+sb[2]+sb[3]) * (1.0f/768.0f);
  float rs = rsqrtf(var + 1e-6f);
  float dv[3] = {d0,d1,d2};
  #pragma unroll
  for (int e=0;e<3;e++){
    int cc = tid + e*256;
    float val = dv[e]*rs*g[cc] + bb[cc];
    size_t oi = (size_t)row*EM + cc;
    if (MODE==0){
      _Float16 h = (_Float16)val;
      hh[oi] = h;
      hl[oi] = (_Float16)((val - (float)h)*2048.0f);
    } else {
      ob[oi] = f2bf(val);
    }
  }
}

// ---------------- QK GEMM, fp16x2 split (fp32-class precision), N=1536 ----------------
__global__ __launch_bounds__(256) void qk_gemm(const _Float16* __restrict__ Ah, const _Float16* __restrict__ Al,
    const _Float16* __restrict__ Wh, const _Float16* __restrict__ Wl, const float* __restrict__ bias,
    float* __restrict__ qo, float* __restrict__ ko){
  __shared__ __align__(16) char smem[65536];
  char* sAh = smem; char* sAl = smem+16384; char* sBh = smem+32768; char* sBl = smem+49152;
  const int tid=threadIdx.x, l=tid&63, w=tid>>6, wm=w>>1, wn=w&1;
  const int m0 = blockIdx.x*128, n0 = blockIdx.y*128;
  const int srow = l>>3, scol = ((l&7)^srow)<<3;   // pre-swizzled source (XOR involution)
  f32x4 a1[4][4] = {}; f32x4 a2[4][4] = {};
  for (int k0=0;k0<EM;k0+=64){
    __syncthreads();
    #pragma unroll
    for (int t=0;t<4;t++){
      size_t ra = (size_t)(m0 + w*32 + t*8 + srow)*EM + k0 + scol;
      size_t rb = (size_t)(n0 + w*32 + t*8 + srow)*EM + k0 + scol;
      int lo = w*4096 + t*1024;
      gll16(Ah+ra, sAh+lo);
      gll16(Al+ra, sAl+lo);
      gll16(Wh+rb, sBh+lo);
      gll16(Wl+rb, sBl+lo);
    }
    __syncthreads();
    #pragma unroll
    for (int ks=0;ks<2;ks++){
      int cb = ks*64 + ((l>>4)<<4);
      f16x8 ah[4], al_[4];
      #pragma unroll
      for (int i=0;i<4;i++){
        int off = sw128(wm*64+i*16+(l&15), cb);
        ah[i]  = *(const f16x8*)(sAh+off);
        al_[i] = *(const f16x8*)(sAl+off);
      }
      #pragma unroll
      for (int j=0;j<4;j++){
        int off = sw128(wn*64+j*16+(l&15), cb);
        f16x8 bh = *(const f16x8*)(sBh+off);
        f16x8 bl = *(const f16x8*)(sBl+off);
        #pragma unroll
        for (int i=0;i<4;i++){
          a1[i][j] = __builtin_amdgcn_mfma_f32_16x16x32_f16(ah[i],  bh, a1[i][j],0,0,0);
          a2[i][j] = __builtin_amdgcn_mfma_f32_16x16x32_f16(ah[i],  bl, a2[i][j],0,0,0);
          a2[i][j] = __builtin_amdgcn_mfma_f32_16x16x32_f16(al_[i], bh, a2[i][j],0,0,0);
        }
      }
    }
  }
  #pragma unroll
  for (int i=0;i<4;i++)
  #pragma unroll
  for (int j=0;j<4;j++)
  #pragma unroll
  for (int rr=0;rr<4;rr++){
    int gm = m0 + wm*64 + i*16 + (l>>4)*4 + rr;
    int gn = n0 + wn*64 + j*16 + (l&15);
    float v = (a1[i][j][rr] + a2[i][j][rr]*4.8828125e-4f)*9.765625e-4f + bias[gn];
    int isk = gn>=768; int gnl = isk ? gn-768 : gn;
    int hh = gnl>>6; int d = gnl&63;
    int b = gm>>11; int ll = gm&2047;
    size_t idx = (((size_t)(b*NHD+hh))*SL + ll)*DHD + d;
    if (!isk) qo[idx] = v*0.125f;   // q pre-scaled by DH^-0.5
    else      ko[idx] = v;
  }
}

// ---------------- V GEMM, fp16 hi-parts only (bf16-class output), N=768 ----------------
__global__ __launch_bounds__(256) void v_gemm(const _Float16* __restrict__ Ah,
    const _Float16* __restrict__ Wh, const float* __restrict__ bias,
    unsigned short* __restrict__ vo){
  __shared__ __align__(16) char smem[32768];
  char* sAh = smem; char* sBh = smem+16384;
  const int tid=threadIdx.x, l=tid&63, w=tid>>6, wm=w>>1, wn=w&1;
  const int m0 = blockIdx.x*128, n0 = blockIdx.y*128;
  const int srow = l>>3, scol = ((l&7)^srow)<<3;
  f32x4 acc[4][4] = {};
  for (int k0=0;k0<EM;k0+=64){
    __syncthreads();
    #pragma unroll
    for (int t=0;t<4;t++){
      size_t ra = (size_t)(m0 + w*32 + t*8 + srow)*EM + k0 + scol;
      size_t rb = (size_t)(n0 + w*32 + t*8 + srow)*EM + k0 + scol;
      int lo = w*4096 + t*1024;
      gll16(Ah+ra, sAh+lo);
      gll16(Wh+rb, sBh+lo);
    }
    __syncthreads();
    #pragma unroll
    for (int ks=0;ks<2;ks++){
      int cb = ks*64 + ((l>>4)<<4);
      f16x8 ah[4], bh[4];
      #pragma unroll
      for (int i=0;i<4;i++){
        ah[i] = *(const f16x8*)(sAh + sw128(wm*64+i*16+(l&15), cb));
        bh[i] = *(const f16x8*)(sBh + sw128(wn*64+i*16+(l&15), cb));
      }
      #pragma unroll
      for (int i=0;i<4;i++)
      #pragma unroll
      for (int j=0;j<4;j++)
        acc[i][j] = __builtin_amdgcn_mfma_f32_16x16x32_f16(ah[i], bh[j], acc[i][j],0,0,0);
    }
  }
  #pragma unroll
  for (int i=0;i<4;i++)
  #pragma unroll
  for (int j=0;j<4;j++)
  #pragma unroll
  for (int rr=0;rr<4;rr++){
    int gm = m0 + wm*64 + i*16 + (l>>4)*4 + rr;
    int gn = n0 + wn*64 + j*16 + (l&15);
    float v = acc[i][j][rr]*9.765625e-4f + bias[gn];
    int hh = gn>>6; int d = gn&63;
    int b = gm>>11; int ll = gm&2047;
    vo[(((size_t)(b*NHD+hh))*SL + ll)*DHD + d] = f2bf(v);
  }
}

// ---------------- squared norms + global max ----------------
__global__ __launch_bounds__(256) void sqmax_kernel(const float* __restrict__ q, const float* __restrict__ k,
    float* __restrict__ qsq, float* __restrict__ ksq, unsigned* __restrict__ scal){
  bool isq = blockIdx.x < 512;
  const float* src = isq ? q : k;
  float* dst = isq ? qsq : ksq;
  int wg = ((blockIdx.x & 511)<<2) + (threadIdx.x>>6);
  int lane = threadIdx.x & 63;
  float mx = 0.f;
  for (int pos = wg; pos < NPOS; pos += 2048){
    float val = src[(size_t)pos*DHD + lane];
    float sq = val*val;
    #pragma unroll
    for (int off=32; off; off>>=1) sq += __shfl_xor(sq, off);
    if (lane==0) dst[pos] = sq;
    mx = fmaxf(mx, sq);
  }
  __shared__ float sm[4];
  if (lane==0) sm[threadIdx.x>>6] = mx;
  __syncthreads();
  if (threadIdx.x==0){
    float m2 = fmaxf(fmaxf(sm[0],sm[1]), fmaxf(sm[2],sm[3]));
    atomicMax(scal + (isq?0:1), __float_as_uint(m2));   // positives: uint order == float order
  }
}

// ---------------- E2LSH hash values ----------------
__global__ __launch_bounds__(256) void hash_kernel(const float* __restrict__ q, const float* __restrict__ k,
    const float* __restrict__ qsq, const float* __restrict__ ksq, const unsigned* __restrict__ scal,
    const float* __restrict__ alpha, const float* __restrict__ beta,
    float* __restrict__ hq, float* __restrict__ hk){
  __shared__ __align__(16) float sal[264];
  __shared__ __align__(16) float sbe[4];
  for (int i=threadIdx.x; i<264; i+=256) sal[i] = alpha[i];
  if (threadIdx.x<4) sbe[threadIdx.x] = beta[threadIdx.x];
  __syncthreads();
  int gw = blockIdx.x*4 + (threadIdx.x>>6);
  int lane = threadIdx.x & 63;
  bool isq = gw < NPOS;
  int pos = isq ? gw : gw - NPOS;
  const float* src = isq ? q : k;
  const float* sqp = isq ? qsq : ksq;
  float m_tot = __uint_as_float(scal[0]) + __uint_as_float(scal[1]);
  float val = src[(size_t)pos*DHD + lane];
  float4 a = *(const float4*)&sal[lane*4];   // alpha[d][0..3]
  float h0 = val*a.x, h1 = val*a.y, h2 = val*a.z, h3 = val*a.w;
  #pragma unroll
  for (int off=32; off; off>>=1){
    h0 += __shfl_xor(h0,off); h1 += __shfl_xor(h1,off);
    h2 += __shfl_xor(h2,off); h3 += __shfl_xor(h3,off);
  }
  if (lane==0){
    float ext = sqrtf(fmaxf(m_tot - sqp[pos], 0.f));
    const float* ae = &sal[(isq?64:65)*4];   // XBOX+ row: 64 for Q, 65 for K
    float* out = isq ? hq : hk;
    out[0*NPOS + pos] = h0 + ext*ae[0] + sbe[0];
    out[1*NPOS + pos] = h1 + ext*ae[1] + sbe[1];
    out[2*NPOS + pos] = h2 + ext*ae[2] + sbe[2];
    out[3*NPOS + pos] = h3 + ext*ae[3] + sbe[3];
  }
}

// ---------------- bitonic argsort of 2048 keys ----------------
__global__ __launch_bounds__(1024) void sort_kernel(const float* __restrict__ hq, const float* __restrict__ hk,
    int* __restrict__ qpos, int* __restrict__ kpos){
  __shared__ float sv[2048];
  __shared__ int si[2048];
  int bid = blockIdx.x;
  bool isq = bid < 192;
  int row = isq ? bid : bid-192;
  const float* h = (isq?hq:hk) + (size_t)row*SL;
  int* op = (isq?qpos:kpos) + (size_t)row*SL;
  for (int i=threadIdx.x; i<SL; i+=1024){ sv[i]=h[i]; si[i]=i; }
  __syncthreads();
  for (int kk=2; kk<=SL; kk<<=1){
    for (int j=kk>>1; j>0; j>>=1){
      int t = threadIdx.x;
      int i1 = ((t & ~(j-1))<<1) | (t & (j-1));
      int i2 = i1 | j;
      bool up = (i1 & kk)==0;
      float a = sv[i1], b = sv[i2];
      int ia = si[i1], ib = si[i2];
      if ((a>b)==up){ sv[i1]=b; sv[i2]=a; si[i1]=ib; si[i2]=ia; }
      __syncthreads();
    }
  }
  for (int i=threadIdx.x; i<SL; i+=1024) op[i]=si[i];
}

// ---------------- within-cluster attention ----------------
__global__ __launch_bounds__(256) void attn_kernel(const float* __restrict__ q, const float* __restrict__ k,
    const unsigned short* __restrict__ v, const int* __restrict__ qpos, const int* __restrict__ kpos,
    unsigned short* __restrict__ oh, float* __restrict__ lseh){
  __shared__ __align__(16) char smem[50176];
  char* qs  = smem;               // [128][64] bf16 (swizzled), later reused as P rows 0..63
  char* ks_ = smem + 16384;       // [128][64] bf16, later reused as P rows 64..127
  char* P   = smem;               // [128][128] bf16 (swizzled 256B rows)
  char* vt  = smem + 32768;       // [64][128] bf16 V^T (swizzled 256B rows)
  int* idxq = (int*)(smem + 49152);
  int* idxk = (int*)(smem + 49664);

  const int tid = threadIdx.x, l = tid&63, w = tid>>6;
  const int bid = blockIdx.x;
  const int c = bid&15, rb = bid>>4, bs = rb%NBS, r = rb/NBS;
  const size_t rowbase = ((size_t)r*NBS + bs)*SL;
  if (tid < 128) idxq[tid] = qpos[rowbase + c*128 + tid];
  else           idxk[tid-128] = kpos[rowbase + c*128 + (tid-128)];
  __syncthreads();

  const float* qb = q + (size_t)bs*SL*DHD;
  const float* kb = k + (size_t)bs*SL*DHD;
  const unsigned short* vb = v + (size_t)bs*SL*DHD;
  #pragma unroll
  for (int p=0;p<8;p++){
    int row = p*16 + (tid>>4); int ch = tid&15;
    {
      int orig = idxq[row];
      float4 f = *(const float4*)(qb + (size_t)orig*DHD + ch*4);
      uint2 pk; pk.x = (unsigned)f2bf(f.x) | ((unsigned)f2bf(f.y)<<16);
      pk.y = (unsigned)f2bf(f.z) | ((unsigned)f2bf(f.w)<<16);
      *(uint2*)(qs + sw128(row, ch*8)) = pk;
    }
    {
      int orig = idxk[row];
      float4 f = *(const float4*)(kb + (size_t)orig*DHD + ch*4);
      uint2 pk; pk.x = (unsigned)f2bf(f.x) | ((unsigned)f2bf(f.y)<<16);
      pk.y = (unsigned)f2bf(f.z) | ((unsigned)f2bf(f.w)<<16);
      *(uint2*)(ks_ + sw128(row, ch*8)) = pk;
    }
    {
      int orig = idxk[row];
      ushort4 vv = *(const ushort4*)(vb + (size_t)orig*DHD + ch*4);
      unsigned short arr[4] = {vv.x, vv.y, vv.z, vv.w};
      #pragma unroll
      for (int ii=0;ii<4;ii++){
        int d = ch*4+ii;
        *(unsigned short*)(vt + sw256(d, row*2)) = arr[ii];   // transpose on the fly
      }
    }
  }
  __syncthreads();

  // S = q_s @ k_s^T  (wave w owns rows w*32..w*32+31)
  f32x4 sc[2][8] = {};
  #pragma unroll
  for (int ks=0;ks<2;ks++){
    int cb = ks*64 + ((l>>4)<<4);
    short8 aq[2];
    aq[0] = *(const short8*)(qs + sw128(w*32 +      (l&15), cb));
    aq[1] = *(const short8*)(qs + sw128(w*32 + 16 + (l&15), cb));
    #pragma unroll
    for (int nj=0;nj<8;nj++){
      short8 bk = *(const short8*)(ks_ + sw128(nj*16+(l&15), cb));
      sc[0][nj] = __builtin_amdgcn_mfma_f32_16x16x32_bf16(aq[0], bk, sc[0][nj],0,0,0);
      sc[1][nj] = __builtin_amdgcn_mfma_f32_16x16x32_bf16(aq[1], bk, sc[1][nj],0,0,0);
    }
  }
  __syncthreads();   // all q_s/k_s reads done before P overwrites the region

  // row-wise softmax (16-lane groups hold a row), normalized P + lse scatter
  #pragma unroll
  for (int mi=0;mi<2;mi++)
  #pragma unroll
  for (int rr=0;rr<4;rr++){
    float mx = -3.0e38f;
    #pragma unroll
    for (int nj=0;nj<8;nj++) mx = fmaxf(mx, sc[mi][nj][rr]);
    #pragma unroll
    for (int off=1; off<16; off<<=1) mx = fmaxf(mx, __shfl_xor(mx, off));
    float s = 0.f;
    #pragma unroll
    for (int nj=0;nj<8;nj++){ float p_ = expf(sc[mi][nj][rr]-mx); sc[mi][nj][rr]=p_; s += p_; }
    #pragma unroll
    for (int off=1; off<16; off<<=1) s += __shfl_xor(s, off);
    float inv = 1.0f/s;
    int row = w*32 + mi*16 + (l>>4)*4 + rr;
    #pragma unroll
    for (int nj=0;nj<8;nj++){
      int col = nj*16 + (l&15);
      *(unsigned short*)(P + sw256(row, col*2)) = f2bf(sc[mi][nj][rr]*inv);
    }
    if ((l&15)==0){
      int orig = idxq[row];
      lseh[rowbase + orig] = mx + logf(s);
    }
  }
  __syncthreads();

  // O = P @ V
  f32x4 o[2][4] = {};
  #pragma unroll
  for (int ks=0;ks<4;ks++){
    int cb = ks*64 + ((l>>4)<<4);
    short8 pa[2];
    pa[0] = *(const short8*)(P + sw256(w*32 +      (l&15), cb));
    pa[1] = *(const short8*)(P + sw256(w*32 + 16 + (l&15), cb));
    #pragma unroll
    for (int nd=0;nd<4;nd++){
      short8 bv = *(const short8*)(vt + sw256(nd*16+(l&15), cb));
      o[0][nd] = __builtin_amdgcn_mfma_f32_16x16x32_bf16(pa[0], bv, o[0][nd],0,0,0);
      o[1][nd] = __builtin_amdgcn_mfma_f32_16x16x32_bf16(pa[1], bv, o[1][nd],0,0,0);
    }
  }
  #pragma unroll
  for (int mi=0;mi<2;mi++)
  #pragma unroll
  for (int nd=0;nd<4;nd++)
  #pragma unroll
  for (int rr=0;rr<4;rr++){
    int row = w*32 + mi*16 + (l>>4)*4 + rr;
    int orig = idxq[row];
    oh[(rowbase + orig)*DHD + nd*16 + (l&15)] = f2bf(o[mi][nd][rr]);
  }
}

// ---------------- merge hash rounds ----------------
__global__ __launch_bounds__(256) void merge_kernel(const unsigned short* __restrict__ oh,
    const float* __restrict__ lseh, unsigned short* __restrict__ attnb){
  int idx = blockIdx.x*256 + threadIdx.x;
  int d = idx&63; int pos = idx>>6; int ll = pos & (SL-1); int bs = pos >> 11;
  float l0 = lseh[0*NPOS+pos], l1 = lseh[1*NPOS+pos], l2 = lseh[2*NPOS+pos], l3 = lseh[3*NPOS+pos];
  float mx = fmaxf(fmaxf(l0,l1),fmaxf(l2,l3));
  float w0 = expf(l0-mx), w1 = expf(l1-mx), w2 = expf(l2-mx), w3 = expf(l3-mx);
  float inv = 1.0f/(w0+w1+w2+w3);
  float acc = (w0*bf2f(oh[((size_t)0*NPOS+pos)*DHD+d]) +
               w1*bf2f(oh[((size_t)1*NPOS+pos)*DHD+d]) +
               w2*bf2f(oh[((size_t)2*NPOS+pos)*DHD+d]) +
               w3*bf2f(oh[((size_t)3*NPOS+pos)*DHD+d]))*inv;
  int b = bs/NHD, hh = bs%NHD;
  attnb[((size_t)(b*SL)+ll)*EM + hh*DHD + d] = f2bf(acc);
}

// ---------------- generic bf16 NT GEMM ----------------
// EPI 0: outf = acc + bias + res (fp32).  EPI 1: outb = bf16(gelu(acc + bias)).
template<int EPI>
__global__ __launch_bounds__(256) void gemm_bf16(const unsigned short* __restrict__ A,
    const unsigned short* __restrict__ Bw, const float* __restrict__ bias,
    const float* __restrict__ res, float* __restrict__ outf, unsigned short* __restrict__ outb,
    int M, int N, int K){
  __shared__ __align__(16) char smem[32768];
  char* sA = smem; char* sB = smem+16384;
  const int tid=threadIdx.x, l=tid&63, w=tid>>6, wm=w>>1, wn=w&1;
  const int m0 = blockIdx.x*128, n0 = blockIdx.y*128;
  const int srow = l>>3, scol = ((l&7)^srow)<<3;
  f32x4 acc[4][4] = {};
  for (int k0=0;k0<K;k0+=64){
    __syncthreads();
    #pragma unroll
    for (int t=0;t<4;t++){
      int lo = w*4096 + t*1024;
      gll16(A  + (size_t)(m0 + w*32 + t*8 + srow)*K + k0 + scol, sA+lo);
      gll16(Bw + (size_t)(n0 + w*32 + t*8 + srow)*K + k0 + scol, sB+lo);
    }
    __syncthreads();
    #pragma unroll
    for (int ks=0;ks<2;ks++){
      int cb = ks*64 + ((l>>4)<<4);
      short8 af[4], bfr[4];
      #pragma unroll
      for (int i=0;i<4;i++){
        af[i]  = *(const short8*)(sA + sw128(wm*64+i*16+(l&15), cb));
        bfr[i] = *(const short8*)(sB + sw128(wn*64+i*16+(l&15), cb));
      }
      #pragma unroll
      for (int i=0;i<4;i++)
      #pragma unroll
      for (int j=0;j<4;j++)
        acc[i][j] = __builtin_amdgcn_mfma_f32_16x16x32_bf16(af[i], bfr[j], acc[i][j],0,0,0);
    }
  }
  #pragma unroll
  for (int i=0;i<4;i++)
  #pragma unroll
  for (int j=0;j<4;j++)
  #pragma unroll
  for (int rr=0;rr<4;rr++){
    int gm = m0 + wm*64 + i*16 + (l>>4)*4 + rr;
    int gn = n0 + wn*64 + j*16 + (l&15);
    float v = acc[i][j][rr] + bias[gn];
    size_t oidx = (size_t)gm*N + gn;
    if (EPI==0) outf[oidx] = v + res[oidx];
    else { float ge = 0.5f*v*(1.0f + erff(v*0.70710678118654752f)); outb[oidx] = f2bf(ge); }
  }
}

extern "C" void kernel_launch(void* const* d_in, const int* in_sizes, int n_in,
                              void* d_out, int out_size, void* d_ws, size_t ws_size,
                              hipStream_t stream){
  const float* x    = (const float*)d_in[0];
  const float* ln1g = (const float*)d_in[1];
  const float* ln1b = (const float*)d_in[2];
  const float* wqkv = (const float*)d_in[3];
  const float* bqkv = (const float*)d_in[4];
  const float* wout = (const float*)d_in[5];
  const float* bout = (const float*)d_in[6];
  const float* ln2g = (const float*)d_in[7];
  const float* ln2b = (const float*)d_in[8];
  const float* w1   = (const float*)d_in[9];
  const float* b1   = (const float*)d_in[10];
  const float* w2   = (const float*)d_in[11];
  const float* b2   = (const float*)d_in[12];
  const float* alpha= (const float*)d_in[13];
  const float* beta = (const float*)d_in[14];
  float* out = (float*)d_out;

  char* ws = (char*)d_ws;
  size_t off = 0;
  auto A = [&](size_t n)->char*{ char* p = ws+off; off += (n+255)&~(size_t)255; return p; };
  _Float16* h_hi = (_Float16*)A(12582912);
  _Float16* h_lo = (_Float16*)A(12582912);
  _Float16* wq_h = (_Float16*)A(3538944);
  _Float16* wq_l = (_Float16*)A(3538944);
  unsigned short* wo_b = (unsigned short*)A(1179648);
  unsigned short* w1_b = (unsigned short*)A(4718592);
  unsigned short* w2_b = (unsigned short*)A(4718592);
  float* qbuf = (float*)A(25165824);
  float* kbuf = (float*)A(25165824);
  unsigned short* vbuf = (unsigned short*)A(12582912);
  float* qsq = (float*)A(393216);
  float* ksq = (float*)A(393216);
  unsigned* scal = (unsigned*)A(256);
  float* hq = (float*)A(1572864);
  float* hk = (float*)A(1572864);
  int* qpos = (int*)A(1572864);
  int* kpos = (int*)A(1572864);
  unsigned short* oh = (unsigned short*)A(50331648);
  float* lseh = (float*)A(1572864);
  // aliases (lifetime-disjoint)
  unsigned short* attnb = vbuf;                 // v dead after attn_kernel
  float* x2 = (float*)oh;                       // oh dead after merge_kernel
  unsigned short* yb = (unsigned short*)h_hi;   // h dead after v_gemm
  unsigned short* ub = (unsigned short*)qbuf;   // q,k dead after attn_kernel (contiguous 48MB span)

  hipMemsetAsync(scal, 0, 8, stream);
  { int n = 2304*768; wsplit_kernel<<<(n+255)/256, 256, 0, stream>>>(wqkv, wq_h, wq_l, n); }
  { int n = 768*768;  tobf_kernel<<<(n+255)/256, 256, 0, stream>>>(wout, wo_b, n); }
  { int n = 3072*768; tobf_kernel<<<(n+255)/256, 256, 0, stream>>>(w1, w1_b, n); }
  { int n = 768*3072; tobf_kernel<<<(n+255)/256, 256, 0, stream>>>(w2, w2_b, n); }
  ln_kernel<0><<<MLROWS, 256, 0, stream>>>(x, ln1g, ln1b, h_hi, h_lo, nullptr);
  qk_gemm<<<dim3(64,12), 256, 0, stream>>>(h_hi, h_lo, wq_h, wq_l, bqkv, qbuf, kbuf);
  v_gemm<<<dim3(64,6), 256, 0, stream>>>(h_hi, wq_h + (size_t)1536*768, bqkv + 1536, vbuf);
  sqmax_kernel<<<1024, 256, 0, stream>>>(qbuf, kbuf, qsq, ksq, scal);
  hash_kernel<<<49152, 256, 0, stream>>>(qbuf, kbuf, qsq, ksq, scal, alpha, beta, hq, hk);
  sort_kernel<<<384, 1024, 0, stream>>>(hq, hk, qpos, kpos);
  attn_kernel<<<3072, 256, 0, stream>>>(qbuf, kbuf, vbuf, qpos, kpos, oh, lseh);
  merge_kernel<<<24576, 256, 0, stream>>>(oh, lseh, attnb);
  gemm_bf16<0><<<dim3(64,6),  256, 0, stream>>>(attnb, wo_b, bout, x,  x2,  nullptr, MLROWS, 768, 768);
  ln_kernel<1><<<MLROWS, 256, 0, stream>>>(x2, ln2g, ln2b, nullptr, nullptr, yb);
  gemm_bf16<1><<<dim3(64,24), 256, 0, stream>>>(yb, w1_b, b1, nullptr, nullptr, ub, MLROWS, 3072, 768);
  gemm_bf16<0><<<dim3(64,6),  256, 0, stream>>>(ub, w2_b, b2, x2, out, nullptr, MLROWS, 768, 3072);
}

// Round 3
// 487.018 us; speedup vs baseline: 1.1412x; 1.0215x over previous
//
#include <hip/hip_runtime.h>
#include <hip/hip_bf16.h>

#define NB 4
#define SL 2048
#define EM 768
#define NHD 12
#define DHD 64
#define MLPD 3072
#define NHASH 4
#define NBS 48        // NB*NHD
#define NPOS 98304    // NBS*SL
#define MLROWS 8192   // NB*SL

typedef __attribute__((ext_vector_type(8))) short short8;
typedef __attribute__((ext_vector_type(8))) _Float16 f16x8;
typedef __attribute__((ext_vector_type(4))) float f32x4;

__device__ __forceinline__ unsigned short f2bf(float x){
  unsigned u = __float_as_uint(x);
  u += 0x7fffu + ((u>>16)&1u);
  return (unsigned short)(u>>16);
}
__device__ __forceinline__ float bf2f(unsigned short s){
  return __uint_as_float(((unsigned)s)<<16);
}
// 128B-row swizzle (8 slots of 16B): conflict-free for col-slice reads
__device__ __forceinline__ int sw128(int row, int colbyte){ return row*128 + (colbyte ^ ((row&7)<<4)); }
__device__ __forceinline__ int sw256(int row, int colbyte){ return row*256 + (colbyte ^ ((row&7)<<4)); }
// 64B-row swizzle (4 slots of 16B): slot ^= (row>>1)&3 -> 2-way (free) on frag reads
__device__ __forceinline__ int sw64(int row, int slot){ return row*64 + ((slot ^ ((row>>1)&3))<<4); }

// async global->LDS, 16B per lane; LDS dest = wave-uniform base + lane*16
__device__ __forceinline__ void gll16(const void* g, const void* l){
  __builtin_amdgcn_global_load_lds(
      (const __attribute__((address_space(1))) void*)(uintptr_t)g,
      (__attribute__((address_space(3))) void*)(unsigned int)(uintptr_t)l,
      16, 0, 0);
}

// ---------------- weight prep ----------------
__global__ __launch_bounds__(256) void wsplit_kernel(const float* __restrict__ w,
    _Float16* __restrict__ wh, _Float16* __restrict__ wl, int n){
  int i = blockIdx.x*256 + threadIdx.x;
  if (i < n){
    float x = w[i]*1024.0f;           // pre-scale keeps lo part out of fp16 denorms
    _Float16 h = (_Float16)x;
    wh[i] = h;
    wl[i] = (_Float16)((x - (float)h)*2048.0f);
  }
}
__global__ __launch_bounds__(256) void tobf_kernel(const float* __restrict__ w,
    unsigned short* __restrict__ o, int n){
  int i = blockIdx.x*256 + threadIdx.x;
  if (i < n) o[i] = f2bf(w[i]);
}

// ---------------- layernorm ----------------
template<int MODE>
__global__ __launch_bounds__(256) void ln_kernel(const float* __restrict__ x,
    const float* __restrict__ g, const float* __restrict__ bb,
    _Float16* __restrict__ hh, _Float16* __restrict__ hl, unsigned short* __restrict__ ob){
  int row = blockIdx.x; int tid = threadIdx.x;
  const float* xr = x + (size_t)row*EM;
  float v0 = xr[tid], v1 = xr[tid+256], v2 = xr[tid+512];
  __shared__ float sb[8];
  float s = v0+v1+v2;
  #pragma unroll
  for (int off=32; off; off>>=1) s += __shfl_down(s, off);
  if ((tid&63)==0) sb[tid>>6] = s;
  __syncthreads();
  float mean = (sb[0]+sb[1]+sb[2]+sb[3]) * (1.0f/768.0f);
  float d0=v0-mean, d1=v1-mean, d2=v2-mean;
  float q_ = d0*d0 + d1*d1 + d2*d2;
  #pragma unroll
  for (int off=32; off; off>>=1) q_ += __shfl_down(q_, off);
  __syncthreads();
  if ((tid&63)==0) sb[tid>>6] = q_;
  __syncthreads();
  float var = (sb[0]+sb[1]+sb[2]+sb[3]) * (1.0f/768.0f);
  float rs = rsqrtf(var + 1e-6f);
  float dv[3] = {d0,d1,d2};
  #pragma unroll
  for (int e=0;e<3;e++){
    int cc = tid + e*256;
    float val = dv[e]*rs*g[cc] + bb[cc];
    size_t oi = (size_t)row*EM + cc;
    if (MODE==0){
      _Float16 h = (_Float16)val;
      hh[oi] = h;
      hl[oi] = (_Float16)((val - (float)h)*2048.0f);
    } else {
      ob[oi] = f2bf(val);
    }
  }
}

// ---------------- fused QKV GEMM ----------------
// blockIdx.y < 12: qk path, fp16x2 split (fp32-class), N-cols [0,1536)
// blockIdx.y >=12: v path, fp16-hi only (bf16-class), N-cols [1536,2304)
// BK=32, double-buffered 2-phase prefetch.
__global__ __launch_bounds__(256) void qkv_gemm(const _Float16* __restrict__ Ah, const _Float16* __restrict__ Al,
    const _Float16* __restrict__ Wh, const _Float16* __restrict__ Wl, const float* __restrict__ bias,
    float* __restrict__ qo, float* __restrict__ ko,
    unsigned short* __restrict__ qb16, unsigned short* __restrict__ kb16, unsigned short* __restrict__ vo){
  __shared__ __align__(16) char smem[65536];
  const int tid=threadIdx.x, l=tid&63, w=tid>>6, wm=w>>1, wn=w&1;
  const int m0 = blockIdx.x*128;
  const int srow = l>>2;                          // source row within 16-row chunk
  const int scol = ((l&3)^((l>>3)&3))<<3;         // pre-swizzled source col (elements)
  // K-step-invariant fragment LDS offsets (sw64)
  int oa[4], ob_[4];
  #pragma unroll
  for (int i=0;i<4;i++){
    int ra = wm*64 + i*16 + (l&15);
    oa[i]  = sw64(ra, l>>4);
    int rb = wn*64 + i*16 + (l&15);
    ob_[i] = sw64(rb, l>>4);
  }
  if (blockIdx.y < 12){
    const int n0 = blockIdx.y*128;
    const _Float16* pAh = Ah + (size_t)(m0 + w*32 + srow)*EM + scol;
    const _Float16* pAl = Al + (size_t)(m0 + w*32 + srow)*EM + scol;
    const _Float16* pBh = Wh + (size_t)(n0 + w*32 + srow)*EM + scol;
    const _Float16* pBl = Wl + (size_t)(n0 + w*32 + srow)*EM + scol;
    f32x4 a1[4][4] = {}; f32x4 a2[4][4] = {};
    auto stage = [&](int buf, int k0){
      char* b = smem + buf*32768 + w*2048;
      #pragma unroll
      for (int c=0;c<2;c++){
        gll16(pAh + k0 + c*16*EM, b +         c*1024);
        gll16(pAl + k0 + c*16*EM, b +  8192 + c*1024);
        gll16(pBh + k0 + c*16*EM, b + 16384 + c*1024);
        gll16(pBl + k0 + c*16*EM, b + 24576 + c*1024);
      }
    };
    auto compute = [&](int buf){
      char* s0 = smem + buf*32768;
      f16x8 ah[4], al2[4];
      #pragma unroll
      for (int i=0;i<4;i++){
        ah[i]  = *(const f16x8*)(s0 + oa[i]);
        al2[i] = *(const f16x8*)(s0 + 8192 + oa[i]);
      }
      #pragma unroll
      for (int j=0;j<4;j++){
        f16x8 bh = *(const f16x8*)(s0 + 16384 + ob_[j]);
        f16x8 bl = *(const f16x8*)(s0 + 24576 + ob_[j]);
        #pragma unroll
        for (int i=0;i<4;i++){
          a1[i][j] = __builtin_amdgcn_mfma_f32_16x16x32_f16(ah[i],  bh, a1[i][j],0,0,0);
          a2[i][j] = __builtin_amdgcn_mfma_f32_16x16x32_f16(ah[i],  bl, a2[i][j],0,0,0);
          a2[i][j] = __builtin_amdgcn_mfma_f32_16x16x32_f16(al2[i], bh, a2[i][j],0,0,0);
        }
      }
    };
    stage(0, 0);
    __syncthreads();
    #pragma unroll 2
    for (int t=0;t<24;t++){
      if (t<23) stage((t+1)&1, (t+1)*32);   // prefetch overlaps compute
      compute(t&1);
      __syncthreads();                       // drains vmcnt + lgkmcnt
    }
    #pragma unroll
    for (int i=0;i<4;i++)
    #pragma unroll
    for (int j=0;j<4;j++)
    #pragma unroll
    for (int rr=0;rr<4;rr++){
      int gm = m0 + wm*64 + i*16 + (l>>4)*4 + rr;
      int gn = n0 + wn*64 + j*16 + (l&15);
      float v = (a1[i][j][rr] + a2[i][j][rr]*4.8828125e-4f)*9.765625e-4f + bias[gn];
      int isk = gn>=768; int gnl = isk ? gn-768 : gn;
      int hh = gnl>>6; int d = gnl&63;
      int b = gm>>11; int ll = gm&2047;
      size_t idx = (((size_t)(b*NHD+hh))*SL + ll)*DHD + d;
      if (!isk){ float qv = v*0.125f; qo[idx] = qv; qb16[idx] = f2bf(qv); }
      else     { ko[idx] = v;         kb16[idx] = f2bf(v); }
    }
  } else {
    const int n0 = (blockIdx.y-12)*128;
    const _Float16* pAh = Ah + (size_t)(m0 + w*32 + srow)*EM + scol;
    const _Float16* pBh = Wh + (size_t)(1536 + n0 + w*32 + srow)*EM + scol;
    f32x4 acc[4][4] = {};
    auto stage = [&](int buf, int k0){
      char* b = smem + buf*16384 + w*2048;
      #pragma unroll
      for (int c=0;c<2;c++){
        gll16(pAh + k0 + c*16*EM, b +        c*1024);
        gll16(pBh + k0 + c*16*EM, b + 8192 + c*1024);
      }
    };
    auto compute = [&](int buf){
      char* s0 = smem + buf*16384;
      f16x8 ah[4];
      #pragma unroll
      for (int i=0;i<4;i++) ah[i] = *(const f16x8*)(s0 + oa[i]);
      #pragma unroll
      for (int j=0;j<4;j++){
        f16x8 bh = *(const f16x8*)(s0 + 8192 + ob_[j]);
        #pragma unroll
        for (int i=0;i<4;i++)
          acc[i][j] = __builtin_amdgcn_mfma_f32_16x16x32_f16(ah[i], bh, acc[i][j],0,0,0);
      }
    };
    stage(0, 0);
    __syncthreads();
    #pragma unroll 2
    for (int t=0;t<24;t++){
      if (t<23) stage((t+1)&1, (t+1)*32);
      compute(t&1);
      __syncthreads();
    }
    #pragma unroll
    for (int i=0;i<4;i++)
    #pragma unroll
    for (int j=0;j<4;j++)
    #pragma unroll
    for (int rr=0;rr<4;rr++){
      int gm = m0 + wm*64 + i*16 + (l>>4)*4 + rr;
      int gn = n0 + wn*64 + j*16 + (l&15);
      float v = acc[i][j][rr]*9.765625e-4f + bias[1536+gn];
      int hh = gn>>6; int d = gn&63;
      int b = gm>>11; int ll = gm&2047;
      vo[(((size_t)(b*NHD+hh))*SL + ll)*DHD + d] = f2bf(v);
    }
  }
}

// ---------------- squared norms + global max ----------------
__global__ __launch_bounds__(256) void sqmax_kernel(const float* __restrict__ q, const float* __restrict__ k,
    float* __restrict__ qsq, float* __restrict__ ksq, unsigned* __restrict__ scal){
  bool isq = blockIdx.x < 512;
  const float* src = isq ? q : k;
  float* dst = isq ? qsq : ksq;
  int wg = ((blockIdx.x & 511)<<2) + (threadIdx.x>>6);
  int lane = threadIdx.x & 63;
  float mx = 0.f;
  for (int pos = wg; pos < NPOS; pos += 2048){
    float val = src[(size_t)pos*DHD + lane];
    float sq = val*val;
    #pragma unroll
    for (int off=32; off; off>>=1) sq += __shfl_xor(sq, off);
    if (lane==0) dst[pos] = sq;
    mx = fmaxf(mx, sq);
  }
  __shared__ float sm[4];
  if (lane==0) sm[threadIdx.x>>6] = mx;
  __syncthreads();
  if (threadIdx.x==0){
    float m2 = fmaxf(fmaxf(sm[0],sm[1]), fmaxf(sm[2],sm[3]));
    atomicMax(scal + (isq?0:1), __float_as_uint(m2));
  }
}

// ---------------- E2LSH hash values (grid-stride) ----------------
__global__ __launch_bounds__(256) void hash_kernel(const float* __restrict__ q, const float* __restrict__ k,
    const float* __restrict__ qsq, const float* __restrict__ ksq, const unsigned* __restrict__ scal,
    const float* __restrict__ alpha, const float* __restrict__ beta,
    float* __restrict__ hq, float* __restrict__ hk){
  __shared__ __align__(16) float sal[264];
  __shared__ __align__(16) float sbe[4];
  for (int i=threadIdx.x; i<264; i+=256) sal[i] = alpha[i];
  if (threadIdx.x<4) sbe[threadIdx.x] = beta[threadIdx.x];
  __syncthreads();
  int wid = blockIdx.x*4 + (threadIdx.x>>6);
  int lane = threadIdx.x & 63;
  float m_tot = __uint_as_float(scal[0]) + __uint_as_float(scal[1]);
  float4 a = *(const float4*)&sal[lane*4];
  for (int gw = wid; gw < 2*NPOS; gw += 3072){
    bool isq = gw < NPOS;
    int pos = isq ? gw : gw - NPOS;
    const float* src = isq ? q : k;
    const float* sqp = isq ? qsq : ksq;
    float val = src[(size_t)pos*DHD + lane];
    float h0 = val*a.x, h1 = val*a.y, h2 = val*a.z, h3 = val*a.w;
    #pragma unroll
    for (int off=32; off; off>>=1){
      h0 += __shfl_xor(h0,off); h1 += __shfl_xor(h1,off);
      h2 += __shfl_xor(h2,off); h3 += __shfl_xor(h3,off);
    }
    if (lane==0){
      float ext = sqrtf(fmaxf(m_tot - sqp[pos], 0.f));
      const float* ae = &sal[(isq?64:65)*4];
      float* out = isq ? hq : hk;
      out[0*NPOS + pos] = h0 + ext*ae[0] + sbe[0];
      out[1*NPOS + pos] = h1 + ext*ae[1] + sbe[1];
      out[2*NPOS + pos] = h2 + ext*ae[2] + sbe[2];
      out[3*NPOS + pos] = h3 + ext*ae[3] + sbe[3];
    }
  }
}

// ---------------- bitonic argsort of 2048 keys ----------------
__global__ __launch_bounds__(1024) void sort_kernel(const float* __restrict__ hq, const float* __restrict__ hk,
    int* __restrict__ qpos, int* __restrict__ kpos){
  __shared__ float sv[2048];
  __shared__ int si[2048];
  int bid = blockIdx.x;
  bool isq = bid < 192;
  int row = isq ? bid : bid-192;
  const float* h = (isq?hq:hk) + (size_t)row*SL;
  int* op = (isq?qpos:kpos) + (size_t)row*SL;
  for (int i=threadIdx.x; i<SL; i+=1024){ sv[i]=h[i]; si[i]=i; }
  __syncthreads();
  for (int kk=2; kk<=SL; kk<<=1){
    for (int j=kk>>1; j>0; j>>=1){
      int t = threadIdx.x;
      int i1 = ((t & ~(j-1))<<1) | (t & (j-1));
      int i2 = i1 | j;
      bool up = (i1 & kk)==0;
      float a = sv[i1], b = sv[i2];
      int ia = si[i1], ib = si[i2];
      if ((a>b)==up){ sv[i1]=b; sv[i2]=a; si[i1]=ib; si[i2]=ia; }
      __syncthreads();
    }
  }
  for (int i=threadIdx.x; i<SL; i+=1024) op[i]=si[i];
}

// ---------------- within-cluster attention (bf16 gathers) ----------------
__global__ __launch_bounds__(256) void attn_kernel(const unsigned short* __restrict__ qb,
    const unsigned short* __restrict__ kb, const unsigned short* __restrict__ v,
    const int* __restrict__ qpos, const int* __restrict__ kpos,
    unsigned short* __restrict__ oh, float* __restrict__ lseh){
  __shared__ __align__(16) char smem[50176];
  char* qs  = smem;               // [128][64] bf16 (sw128), later reused as P rows 0..63
  char* ks_ = smem + 16384;       // [128][64] bf16, later reused as P rows 64..127
  char* P   = smem;               // [128][128] bf16 (sw256 rows)
  char* vt  = smem + 32768;       // [64][128] bf16 V^T (sw256 rows)
  int* idxq = (int*)(smem + 49152);
  int* idxk = (int*)(smem + 49664);

  const int tid = threadIdx.x, l = tid&63, w = tid>>6;
  const int bid = blockIdx.x;
  const int c = bid&15, rb = bid>>4, bs = rb%NBS, r = rb/NBS;
  const size_t rowbase = ((size_t)r*NBS + bs)*SL;
  if (tid < 128) idxq[tid] = qpos[rowbase + c*128 + tid];
  else           idxk[tid-128] = kpos[rowbase + c*128 + (tid-128)];
  __syncthreads();

  const unsigned short* qbb = qb + (size_t)bs*SL*DHD;
  const unsigned short* kbb = kb + (size_t)bs*SL*DHD;
  const unsigned short* vb  = v  + (size_t)bs*SL*DHD;
  #pragma unroll
  for (int p=0;p<8;p++){
    int row = p*16 + (tid>>4); int ch = tid&15;
    {
      int orig = idxq[row];
      uint2 u = *(const uint2*)(qbb + (size_t)orig*DHD + ch*4);
      *(uint2*)(qs + sw128(row, ch*8)) = u;
    }
    {
      int orig = idxk[row];
      uint2 u = *(const uint2*)(kbb + (size_t)orig*DHD + ch*4);
      *(uint2*)(ks_ + sw128(row, ch*8)) = u;
    }
    {
      int orig = idxk[row];
      ushort4 vv = *(const ushort4*)(vb + (size_t)orig*DHD + ch*4);
      unsigned short arr[4] = {vv.x, vv.y, vv.z, vv.w};
      #pragma unroll
      for (int ii=0;ii<4;ii++){
        int d = ch*4+ii;
        *(unsigned short*)(vt + sw256(d, row*2)) = arr[ii];
      }
    }
  }
  __syncthreads();

  // S = q_s @ k_s^T
  f32x4 sc[2][8] = {};
  #pragma unroll
  for (int ks=0;ks<2;ks++){
    int cb = ks*64 + ((l>>4)<<4);
    short8 aq[2];
    aq[0] = *(const short8*)(qs + sw128(w*32 +      (l&15), cb));
    aq[1] = *(const short8*)(qs + sw128(w*32 + 16 + (l&15), cb));
    #pragma unroll
    for (int nj=0;nj<8;nj++){
      short8 bk = *(const short8*)(ks_ + sw128(nj*16+(l&15), cb));
      sc[0][nj] = __builtin_amdgcn_mfma_f32_16x16x32_bf16(aq[0], bk, sc[0][nj],0,0,0);
      sc[1][nj] = __builtin_amdgcn_mfma_f32_16x16x32_bf16(aq[1], bk, sc[1][nj],0,0,0);
    }
  }
  __syncthreads();

  // row-wise softmax (16-lane groups hold a row)
  #pragma unroll
  for (int mi=0;mi<2;mi++)
  #pragma unroll
  for (int rr=0;rr<4;rr++){
    float mx = -3.0e38f;
    #pragma unroll
    for (int nj=0;nj<8;nj++) mx = fmaxf(mx, sc[mi][nj][rr]);
    #pragma unroll
    for (int off=1; off<16; off<<=1) mx = fmaxf(mx, __shfl_xor(mx, off));
    float s = 0.f;
    #pragma unroll
    for (int nj=0;nj<8;nj++){ float p_ = expf(sc[mi][nj][rr]-mx); sc[mi][nj][rr]=p_; s += p_; }
    #pragma unroll
    for (int off=1; off<16; off<<=1) s += __shfl_xor(s, off);
    float inv = 1.0f/s;
    int row = w*32 + mi*16 + (l>>4)*4 + rr;
    #pragma unroll
    for (int nj=0;nj<8;nj++){
      int col = nj*16 + (l&15);
      *(unsigned short*)(P + sw256(row, col*2)) = f2bf(sc[mi][nj][rr]*inv);
    }
    if ((l&15)==0){
      int orig = idxq[row];
      lseh[rowbase + orig] = mx + logf(s);
    }
  }
  __syncthreads();

  // O = P @ V
  f32x4 o[2][4] = {};
  #pragma unroll
  for (int ks=0;ks<4;ks++){
    int cb = ks*64 + ((l>>4)<<4);
    short8 pa[2];
    pa[0] = *(const short8*)(P + sw256(w*32 +      (l&15), cb));
    pa[1] = *(const short8*)(P + sw256(w*32 + 16 + (l&15), cb));
    #pragma unroll
    for (int nd=0;nd<4;nd++){
      short8 bv = *(const short8*)(vt + sw256(nd*16+(l&15), cb));
      o[0][nd] = __builtin_amdgcn_mfma_f32_16x16x32_bf16(pa[0], bv, o[0][nd],0,0,0);
      o[1][nd] = __builtin_amdgcn_mfma_f32_16x16x32_bf16(pa[1], bv, o[1][nd],0,0,0);
    }
  }
  #pragma unroll
  for (int mi=0;mi<2;mi++)
  #pragma unroll
  for (int nd=0;nd<4;nd++)
  #pragma unroll
  for (int rr=0;rr<4;rr++){
    int row = w*32 + mi*16 + (l>>4)*4 + rr;
    int orig = idxq[row];
    oh[(rowbase + orig)*DHD + nd*16 + (l&15)] = f2bf(o[mi][nd][rr]);
  }
}

// ---------------- merge hash rounds ----------------
__global__ __launch_bounds__(256) void merge_kernel(const unsigned short* __restrict__ oh,
    const float* __restrict__ lseh, unsigned short* __restrict__ attnb){
  int idx = blockIdx.x*256 + threadIdx.x;
  int d = idx&63; int pos = idx>>6; int ll = pos & (SL-1); int bs = pos >> 11;
  float l0 = lseh[0*NPOS+pos], l1 = lseh[1*NPOS+pos], l2 = lseh[2*NPOS+pos], l3 = lseh[3*NPOS+pos];
  float mx = fmaxf(fmaxf(l0,l1),fmaxf(l2,l3));
  float w0 = expf(l0-mx), w1 = expf(l1-mx), w2 = expf(l2-mx), w3 = expf(l3-mx);
  float inv = 1.0f/(w0+w1+w2+w3);
  float acc = (w0*bf2f(oh[((size_t)0*NPOS+pos)*DHD+d]) +
               w1*bf2f(oh[((size_t)1*NPOS+pos)*DHD+d]) +
               w2*bf2f(oh[((size_t)2*NPOS+pos)*DHD+d]) +
               w3*bf2f(oh[((size_t)3*NPOS+pos)*DHD+d]))*inv;
  int b = bs/NHD, hh = bs%NHD;
  attnb[((size_t)(b*SL)+ll)*EM + hh*DHD + d] = f2bf(acc);
}

// ---------------- generic bf16 NT GEMM, templated tile-N ----------------
// EPI 0: outf = acc + bias + res (fp32).  EPI 1: outb = bf16(gelu(acc + bias)).
template<int EPI, int BN>
__global__ __launch_bounds__(256) void gemm_bf16(const unsigned short* __restrict__ A,
    const unsigned short* __restrict__ Bw, const float* __restrict__ bias,
    const float* __restrict__ res, float* __restrict__ outf, unsigned short* __restrict__ outb,
    int M, int N, int K){
  constexpr int NJ = BN/32;
  __shared__ __align__(16) char smem[16384 + BN*128];
  char* sA = smem; char* sB = smem + 16384;
  const int tid=threadIdx.x, l=tid&63, w=tid>>6, wm=w>>1, wn=w&1;
  const int m0 = blockIdx.x*128, n0 = blockIdx.y*BN;
  const int srow = l>>3, scol = ((l&7)^srow)<<3;
  f32x4 acc[4][NJ] = {};
  const unsigned short* pA = A  + (size_t)(m0 + w*32 + srow)*K + scol;
  const unsigned short* pB = Bw + (size_t)(n0 + w*(BN/4) + srow)*K + scol;
  for (int k0=0;k0<K;k0+=64){
    __syncthreads();
    #pragma unroll
    for (int c=0;c<4;c++)
      gll16(pA + k0 + c*8*K, sA + w*4096 + c*1024);
    #pragma unroll
    for (int c=0;c<BN/32;c++)
      gll16(pB + k0 + c*8*K, sB + w*(BN*32) + c*1024);
    __syncthreads();
    #pragma unroll
    for (int ks=0;ks<2;ks++){
      int cb = ks*64 + ((l>>4)<<4);
      short8 af[4], bfr[NJ];
      #pragma unroll
      for (int i=0;i<4;i++)
        af[i]  = *(const short8*)(sA + sw128(wm*64+i*16+(l&15), cb));
      #pragma unroll
      for (int j=0;j<NJ;j++)
        bfr[j] = *(const short8*)(sB + sw128(wn*(BN/2)+j*16+(l&15), cb));
      #pragma unroll
      for (int i=0;i<4;i++)
      #pragma unroll
      for (int j=0;j<NJ;j++)
        acc[i][j] = __builtin_amdgcn_mfma_f32_16x16x32_bf16(af[i], bfr[j], acc[i][j],0,0,0);
    }
  }
  #pragma unroll
  for (int i=0;i<4;i++)
  #pragma unroll
  for (int j=0;j<NJ;j++)
  #pragma unroll
  for (int rr=0;rr<4;rr++){
    int gm = m0 + wm*64 + i*16 + (l>>4)*4 + rr;
    int gn = n0 + wn*(BN/2) + j*16 + (l&15);
    float v = acc[i][j][rr] + bias[gn];
    size_t oidx = (size_t)gm*N + gn;
    if (EPI==0) outf[oidx] = v + res[oidx];
    else { float ge = 0.5f*v*(1.0f + erff(v*0.70710678118654752f)); outb[oidx] = f2bf(ge); }
  }
}

extern "C" void kernel_launch(void* const* d_in, const int* in_sizes, int n_in,
                              void* d_out, int out_size, void* d_ws, size_t ws_size,
                              hipStream_t stream){
  const float* x    = (const float*)d_in[0];
  const float* ln1g = (const float*)d_in[1];
  const float* ln1b = (const float*)d_in[2];
  const float* wqkv = (const float*)d_in[3];
  const float* bqkv = (const float*)d_in[4];
  const float* wout = (const float*)d_in[5];
  const float* bout = (const float*)d_in[6];
  const float* ln2g = (const float*)d_in[7];
  const float* ln2b = (const float*)d_in[8];
  const float* w1   = (const float*)d_in[9];
  const float* b1   = (const float*)d_in[10];
  const float* w2   = (const float*)d_in[11];
  const float* b2   = (const float*)d_in[12];
  const float* alpha= (const float*)d_in[13];
  const float* beta = (const float*)d_in[14];
  float* out = (float*)d_out;

  char* ws = (char*)d_ws;
  size_t off = 0;
  auto A = [&](size_t n)->char*{ char* p = ws+off; off += (n+255)&~(size_t)255; return p; };
  _Float16* h_hi = (_Float16*)A(12582912);
  _Float16* h_lo = (_Float16*)A(12582912);
  _Float16* wq_h = (_Float16*)A(3538944);
  _Float16* wq_l = (_Float16*)A(3538944);
  unsigned short* wo_b = (unsigned short*)A(1179648);
  unsigned short* w1_b = (unsigned short*)A(4718592);
  unsigned short* w2_b = (unsigned short*)A(4718592);
  float* qbuf = (float*)A(25165824);
  float* kbuf = (float*)A(25165824);
  unsigned short* vbuf = (unsigned short*)A(12582912);
  unsigned short* qb16 = (unsigned short*)A(12582912);
  unsigned short* kb16 = (unsigned short*)A(12582912);
  float* qsq = (float*)A(393216);
  float* ksq = (float*)A(393216);
  unsigned* scal = (unsigned*)A(256);
  float* hq = (float*)A(1572864);
  float* hk = (float*)A(1572864);
  int* qpos = (int*)A(1572864);
  int* kpos = (int*)A(1572864);
  unsigned short* oh = (unsigned short*)A(50331648);
  float* lseh = (float*)A(1572864);
  // aliases (lifetime-disjoint)
  unsigned short* attnb = vbuf;                 // v dead after attn_kernel
  float* x2 = (float*)oh;                       // oh dead after merge_kernel
  unsigned short* yb = (unsigned short*)h_hi;   // h dead after qkv_gemm
  unsigned short* ub = (unsigned short*)qbuf;   // q,k dead after attn_kernel

  hipMemsetAsync(scal, 0, 8, stream);
  { int n = 2304*768; wsplit_kernel<<<(n+255)/256, 256, 0, stream>>>(wqkv, wq_h, wq_l, n); }
  { int n = 768*768;  tobf_kernel<<<(n+255)/256, 256, 0, stream>>>(wout, wo_b, n); }
  { int n = 3072*768; tobf_kernel<<<(n+255)/256, 256, 0, stream>>>(w1, w1_b, n); }
  { int n = 768*3072; tobf_kernel<<<(n+255)/256, 256, 0, stream>>>(w2, w2_b, n); }
  ln_kernel<0><<<MLROWS, 256, 0, stream>>>(x, ln1g, ln1b, h_hi, h_lo, nullptr);
  qkv_gemm<<<dim3(64,18), 256, 0, stream>>>(h_hi, h_lo, wq_h, wq_l, bqkv,
                                            qbuf, kbuf, qb16, kb16, vbuf);
  sqmax_kernel<<<1024, 256, 0, stream>>>(qbuf, kbuf, qsq, ksq, scal);
  hash_kernel<<<768, 256, 0, stream>>>(qbuf, kbuf, qsq, ksq, scal, alpha, beta, hq, hk);
  sort_kernel<<<384, 1024, 0, stream>>>(hq, hk, qpos, kpos);
  attn_kernel<<<3072, 256, 0, stream>>>(qb16, kb16, vbuf, qpos, kpos, oh, lseh);
  merge_kernel<<<24576, 256, 0, stream>>>(oh, lseh, attnb);
  gemm_bf16<0,64><<<dim3(64,12),  256, 0, stream>>>(attnb, wo_b, bout, x,  x2,  nullptr, MLROWS, 768, 768);
  ln_kernel<1><<<MLROWS, 256, 0, stream>>>(x2, ln2g, ln2b, nullptr, nullptr, yb);
  gemm_bf16<1,128><<<dim3(64,24), 256, 0, stream>>>(yb, w1_b, b1, nullptr, nullptr, ub, MLROWS, 3072, 768);
  gemm_bf16<0,64><<<dim3(64,12),  256, 0, stream>>>(ub, w2_b, b2, x2, out, nullptr, MLROWS, 768, 3072);
}

// Round 4
// 403.876 us; speedup vs baseline: 1.3761x; 1.2059x over previous
//
#include <hip/hip_runtime.h>
#include <hip/hip_bf16.h>

#define NB 4
#define SL 2048
#define EM 768
#define NHD 12
#define DHD 64
#define MLPD 3072
#define NHASH 4
#define NBS 48        // NB*NHD
#define NPOS 98304    // NBS*SL
#define MLROWS 8192   // NB*SL

typedef __attribute__((ext_vector_type(8))) short short8;
typedef __attribute__((ext_vector_type(8))) _Float16 f16x8;
typedef __attribute__((ext_vector_type(4))) float f32x4;

__device__ __forceinline__ unsigned short f2bf(float x){
  unsigned u = __float_as_uint(x);
  u += 0x7fffu + ((u>>16)&1u);
  return (unsigned short)(u>>16);
}
__device__ __forceinline__ float bf2f(unsigned short s){
  return __uint_as_float(((unsigned)s)<<16);
}
// 128B-row swizzle (8 slots of 16B): conflict-free for col-slice reads
__device__ __forceinline__ int sw128(int row, int colbyte){ return row*128 + (colbyte ^ ((row&7)<<4)); }
__device__ __forceinline__ int sw256(int row, int colbyte){ return row*256 + (colbyte ^ ((row&7)<<4)); }
// 64B-row swizzle (4 slots of 16B): slot ^= (row>>1)&3 -> 2-way (free) on frag reads
__device__ __forceinline__ int sw64(int row, int slot){ return row*64 + ((slot ^ ((row>>1)&3))<<4); }

// async global->LDS, 16B per lane; LDS dest = wave-uniform base + lane*16
__device__ __forceinline__ void gll16(const void* g, const void* l){
  __builtin_amdgcn_global_load_lds(
      (const __attribute__((address_space(1))) void*)(uintptr_t)g,
      (__attribute__((address_space(3))) void*)(unsigned int)(uintptr_t)l,
      16, 0, 0);
}

// ---------------- weight prep ----------------
__global__ __launch_bounds__(256) void wsplit_kernel(const float* __restrict__ w,
    _Float16* __restrict__ wh, _Float16* __restrict__ wl, int n){
  int i = blockIdx.x*256 + threadIdx.x;
  if (i < n){
    float x = w[i]*1024.0f;           // pre-scale keeps lo part out of fp16 denorms
    _Float16 h = (_Float16)x;
    wh[i] = h;
    wl[i] = (_Float16)((x - (float)h)*2048.0f);
  }
}
__global__ __launch_bounds__(256) void tobf_kernel(const float* __restrict__ w,
    unsigned short* __restrict__ o, int n){
  int i = blockIdx.x*256 + threadIdx.x;
  if (i < n) o[i] = f2bf(w[i]);
}

// ---------------- layernorm ----------------
template<int MODE>
__global__ __launch_bounds__(256) void ln_kernel(const float* __restrict__ x,
    const float* __restrict__ g, const float* __restrict__ bb,
    _Float16* __restrict__ hh, _Float16* __restrict__ hl, unsigned short* __restrict__ ob){
  int row = blockIdx.x; int tid = threadIdx.x;
  const float* xr = x + (size_t)row*EM;
  float v0 = xr[tid], v1 = xr[tid+256], v2 = xr[tid+512];
  __shared__ float sb[8];
  float s = v0+v1+v2;
  #pragma unroll
  for (int off=32; off; off>>=1) s += __shfl_down(s, off);
  if ((tid&63)==0) sb[tid>>6] = s;
  __syncthreads();
  float mean = (sb[0]+sb[1]+sb[2]+sb[3]) * (1.0f/768.0f);
  float d0=v0-mean, d1=v1-mean, d2=v2-mean;
  float q_ = d0*d0 + d1*d1 + d2*d2;
  #pragma unroll
  for (int off=32; off; off>>=1) q_ += __shfl_down(q_, off);
  __syncthreads();
  if ((tid&63)==0) sb[tid>>6] = q_;
  __syncthreads();
  float var = (sb[0]+sb[1]+sb[2]+sb[3]) * (1.0f/768.0f);
  float rs = rsqrtf(var + 1e-6f);
  float dv[3] = {d0,d1,d2};
  #pragma unroll
  for (int e=0;e<3;e++){
    int cc = tid + e*256;
    float val = dv[e]*rs*g[cc] + bb[cc];
    size_t oi = (size_t)row*EM + cc;
    if (MODE==0){
      _Float16 h = (_Float16)val;
      hh[oi] = h;
      hl[oi] = (_Float16)((val - (float)h)*2048.0f);
    } else {
      ob[oi] = f2bf(val);
    }
  }
}

// ---------------- fused QKV GEMM + norms/hash partials in epilogue ----------------
// blockIdx.y < 12: qk path, fp16x2 split (fp32-class), N-cols [0,1536)
// blockIdx.y >=12: v path, fp16-hi only (bf16-class), N-cols [1536,2304)
__global__ __launch_bounds__(256) void qkv_gemm(const _Float16* __restrict__ Ah, const _Float16* __restrict__ Al,
    const _Float16* __restrict__ Wh, const _Float16* __restrict__ Wl, const float* __restrict__ bias,
    const float* __restrict__ alphag,
    unsigned short* __restrict__ qb16, unsigned short* __restrict__ kb16, unsigned short* __restrict__ vo,
    float* __restrict__ qsq, float* __restrict__ ksq, unsigned* __restrict__ scal,
    float* __restrict__ hqp, float* __restrict__ hkp){
  __shared__ __align__(16) char smem[65536];
  const int tid=threadIdx.x, l=tid&63, w=tid>>6, wm=w>>1, wn=w&1;
  const int m0 = blockIdx.x*128;
  const int srow = l>>2;                          // source row within 16-row chunk
  const int scol = ((l&3)^((l>>3)&3))<<3;         // pre-swizzled source col (elements)
  // K-step-invariant fragment LDS offsets (sw64)
  int oa[4], ob_[4];
  #pragma unroll
  for (int i=0;i<4;i++){
    int ra = wm*64 + i*16 + (l&15);
    oa[i]  = sw64(ra, l>>4);
    int rb = wn*64 + i*16 + (l&15);
    ob_[i] = sw64(rb, l>>4);
  }
  if (blockIdx.y < 12){
    const int n0 = blockIdx.y*128;
    const _Float16* pAh = Ah + (size_t)(m0 + w*32 + srow)*EM + scol;
    const _Float16* pAl = Al + (size_t)(m0 + w*32 + srow)*EM + scol;
    const _Float16* pBh = Wh + (size_t)(n0 + w*32 + srow)*EM + scol;
    const _Float16* pBl = Wl + (size_t)(n0 + w*32 + srow)*EM + scol;
    f32x4 a1[4][4] = {}; f32x4 a2[4][4] = {};
    auto stage = [&](int buf, int k0){
      char* b = smem + buf*32768 + w*2048;
      #pragma unroll
      for (int c=0;c<2;c++){
        gll16(pAh + k0 + c*16*EM, b +         c*1024);
        gll16(pAl + k0 + c*16*EM, b +  8192 + c*1024);
        gll16(pBh + k0 + c*16*EM, b + 16384 + c*1024);
        gll16(pBl + k0 + c*16*EM, b + 24576 + c*1024);
      }
    };
    auto compute = [&](int buf){
      char* s0 = smem + buf*32768;
      f16x8 ah[4], al2[4];
      #pragma unroll
      for (int i=0;i<4;i++){
        ah[i]  = *(const f16x8*)(s0 + oa[i]);
        al2[i] = *(const f16x8*)(s0 + 8192 + oa[i]);
      }
      #pragma unroll
      for (int j=0;j<4;j++){
        f16x8 bh = *(const f16x8*)(s0 + 16384 + ob_[j]);
        f16x8 bl = *(const f16x8*)(s0 + 24576 + ob_[j]);
        #pragma unroll
        for (int i=0;i<4;i++){
          a1[i][j] = __builtin_amdgcn_mfma_f32_16x16x32_f16(ah[i],  bh, a1[i][j],0,0,0);
          a2[i][j] = __builtin_amdgcn_mfma_f32_16x16x32_f16(ah[i],  bl, a2[i][j],0,0,0);
          a2[i][j] = __builtin_amdgcn_mfma_f32_16x16x32_f16(al2[i], bh, a2[i][j],0,0,0);
        }
      }
    };
    stage(0, 0);
    __syncthreads();
    #pragma unroll 2
    for (int t=0;t<24;t++){
      if (t<23) stage((t+1)&1, (t+1)*32);   // prefetch overlaps compute
      compute(t&1);
      __syncthreads();                       // drains vmcnt + lgkmcnt
    }
    // ---- epilogue: bf16 q/k + sq + hash projections ----
    float* sal = (float*)smem;               // reuse LDS for alpha (264 f32)
    for (int i2=tid; i2<264; i2+=256) sal[i2] = alphag[i2];
    __syncthreads();
    const bool isq = (blockIdx.y < 6);
    const float so = isq ? 0.125f : 1.0f;    // q pre-scaled by DH^-0.5
    unsigned short* ob16 = isq ? qb16 : kb16;
    float* sqout = isq ? qsq : ksq;
    float* hpout = isq ? hqp : hkp;
    const int gn0 = n0 + wn*64;
    const int hh = (isq ? gn0 : gn0-768)>>6;
    float mx = 0.f;
    #pragma unroll
    for (int i=0;i<4;i++)
    #pragma unroll
    for (int rr=0;rr<4;rr++){
      int gm = m0 + wm*64 + i*16 + (l>>4)*4 + rr;
      int b = gm>>11, ll = gm&2047;
      size_t pos = ((size_t)(b*NHD+hh))*SL + ll;
      float vv[4];
      float sq_p=0.f, p0=0.f, p1=0.f, p2=0.f, p3=0.f;
      #pragma unroll
      for (int j=0;j<4;j++){
        int gn = gn0 + j*16 + (l&15);
        float v = (a1[i][j][rr] + a2[i][j][rr]*4.8828125e-4f)*9.765625e-4f + bias[gn];
        v *= so;
        vv[j] = v;
        int d = j*16 + (l&15);
        sq_p += v*v;
        p0 += v*sal[d*4+0]; p1 += v*sal[d*4+1];
        p2 += v*sal[d*4+2]; p3 += v*sal[d*4+3];
      }
      #pragma unroll
      for (int j=0;j<4;j++)
        ob16[pos*DHD + j*16 + (l&15)] = f2bf(vv[j]);
      #pragma unroll
      for (int off2=1; off2<16; off2<<=1){
        sq_p += __shfl_xor(sq_p, off2);
        p0 += __shfl_xor(p0, off2); p1 += __shfl_xor(p1, off2);
        p2 += __shfl_xor(p2, off2); p3 += __shfl_xor(p3, off2);
      }
      mx = fmaxf(mx, sq_p);
      if ((l&15)==0){
        sqout[pos] = sq_p;
        hpout[0*NPOS+pos] = p0; hpout[1*NPOS+pos] = p1;
        hpout[2*NPOS+pos] = p2; hpout[3*NPOS+pos] = p3;
      }
    }
    mx = fmaxf(mx, __shfl_xor(mx, 16));
    mx = fmaxf(mx, __shfl_xor(mx, 32));
    float* smx = (float*)(smem + 1088);
    if (l==0) smx[w] = mx;
    __syncthreads();
    if (tid==0){
      float m2 = fmaxf(fmaxf(smx[0],smx[1]), fmaxf(smx[2],smx[3]));
      atomicMax(scal + (isq?0:1), __float_as_uint(m2));  // positives: uint order == float order
    }
  } else {
    const int n0 = (blockIdx.y-12)*128;
    const _Float16* pAh = Ah + (size_t)(m0 + w*32 + srow)*EM + scol;
    const _Float16* pBh = Wh + (size_t)(1536 + n0 + w*32 + srow)*EM + scol;
    f32x4 acc[4][4] = {};
    auto stage = [&](int buf, int k0){
      char* b = smem + buf*16384 + w*2048;
      #pragma unroll
      for (int c=0;c<2;c++){
        gll16(pAh + k0 + c*16*EM, b +        c*1024);
        gll16(pBh + k0 + c*16*EM, b + 8192 + c*1024);
      }
    };
    auto compute = [&](int buf){
      char* s0 = smem + buf*16384;
      f16x8 ah[4];
      #pragma unroll
      for (int i=0;i<4;i++) ah[i] = *(const f16x8*)(s0 + oa[i]);
      #pragma unroll
      for (int j=0;j<4;j++){
        f16x8 bh = *(const f16x8*)(s0 + 8192 + ob_[j]);
        #pragma unroll
        for (int i=0;i<4;i++)
          acc[i][j] = __builtin_amdgcn_mfma_f32_16x16x32_f16(ah[i], bh, acc[i][j],0,0,0);
      }
    };
    stage(0, 0);
    __syncthreads();
    #pragma unroll 2
    for (int t=0;t<24;t++){
      if (t<23) stage((t+1)&1, (t+1)*32);
      compute(t&1);
      __syncthreads();
    }
    #pragma unroll
    for (int i=0;i<4;i++)
    #pragma unroll
    for (int j=0;j<4;j++)
    #pragma unroll
    for (int rr=0;rr<4;rr++){
      int gm = m0 + wm*64 + i*16 + (l>>4)*4 + rr;
      int gn = n0 + wn*64 + j*16 + (l&15);
      float v = acc[i][j][rr]*9.765625e-4f + bias[1536+gn];
      int hh = gn>>6; int d = gn&63;
      int b = gm>>11; int ll = gm&2047;
      vo[(((size_t)(b*NHD+hh))*SL + ll)*DHD + d] = f2bf(v);
    }
  }
}

// ---------------- hash finalize: h = proj + ext*ae + be ----------------
__global__ __launch_bounds__(256) void hashfin_kernel(const float* __restrict__ qsq,
    const float* __restrict__ ksq, const unsigned* __restrict__ scal,
    const float* __restrict__ hqp, const float* __restrict__ hkp,
    const float* __restrict__ alpha, const float* __restrict__ beta,
    float* __restrict__ hq, float* __restrict__ hk){
  int idx = blockIdx.x*256 + threadIdx.x;
  bool isq = idx < NPOS;
  int pos = isq ? idx : idx - NPOS;
  float m_tot = __uint_as_float(scal[0]) + __uint_as_float(scal[1]);
  float sq = (isq ? qsq : ksq)[pos];
  float ext = sqrtf(fmaxf(m_tot - sq, 0.f));
  const float* hp = isq ? hqp : hkp;
  float* out = isq ? hq : hk;
  const float* ae = alpha + (isq?64:65)*4;   // XBOX+ row: 64 for Q, 65 for K
  #pragma unroll
  for (int r=0;r<4;r++)
    out[r*NPOS + pos] = hp[r*NPOS + pos] + ext*ae[r] + beta[r];
}

// ---------------- bitonic argsort of 2048 keys (u64-packed, stable) ----------------
__global__ __launch_bounds__(1024) void sort_kernel(const float* __restrict__ hq, const float* __restrict__ hk,
    int* __restrict__ qpos, int* __restrict__ kpos){
  __shared__ unsigned long long sv[2048];
  int bid = blockIdx.x;
  bool isq = bid < 192;
  int row = isq ? bid : bid-192;
  const float* h = (isq?hq:hk) + (size_t)row*SL;
  int* op = (isq?qpos:kpos) + (size_t)row*SL;
  for (int i=threadIdx.x; i<SL; i+=1024){
    unsigned u = __float_as_uint(h[i]);
    u ^= ((unsigned)((int)u>>31)) | 0x80000000u;   // monotone unsigned order
    sv[i] = ((unsigned long long)u<<32) | (unsigned)i;
  }
  __syncthreads();
  for (int kk=2; kk<=SL; kk<<=1){
    for (int j=kk>>1; j>0; j>>=1){
      int t = threadIdx.x;
      int i1 = ((t & ~(j-1))<<1) | (t & (j-1));
      int i2 = i1 | j;
      bool up = (i1 & kk)==0;
      unsigned long long a = sv[i1], b = sv[i2];
      if ((a>b)==up){ sv[i1]=b; sv[i2]=a; }
      __syncthreads();
    }
  }
  for (int i=threadIdx.x; i<SL; i+=1024) op[i] = (int)(unsigned)(sv[i] & 0xFFFFFFFFu);
}

// ---------------- within-cluster attention (bf16 gathers) ----------------
__global__ __launch_bounds__(256) void attn_kernel(const unsigned short* __restrict__ qb,
    const unsigned short* __restrict__ kb, const unsigned short* __restrict__ v,
    const int* __restrict__ qpos, const int* __restrict__ kpos,
    unsigned short* __restrict__ oh, float* __restrict__ lseh){
  __shared__ __align__(16) char smem[50176];
  char* qs  = smem;               // [128][64] bf16 (sw128), later reused as P rows 0..63
  char* ks_ = smem + 16384;       // [128][64] bf16, later reused as P rows 64..127
  char* P   = smem;               // [128][128] bf16 (sw256 rows)
  char* vt  = smem + 32768;       // [64][128] bf16 V^T (sw256 rows)
  int* idxq = (int*)(smem + 49152);
  int* idxk = (int*)(smem + 49664);

  const int tid = threadIdx.x, l = tid&63, w = tid>>6;
  const int bid = blockIdx.x;
  const int c = bid&15, rb = bid>>4, bs = rb%NBS, r = rb/NBS;
  const size_t rowbase = ((size_t)r*NBS + bs)*SL;
  if (tid < 128) idxq[tid] = qpos[rowbase + c*128 + tid];
  else           idxk[tid-128] = kpos[rowbase + c*128 + (tid-128)];
  __syncthreads();

  const unsigned short* qbb = qb + (size_t)bs*SL*DHD;
  const unsigned short* kbb = kb + (size_t)bs*SL*DHD;
  const unsigned short* vb  = v  + (size_t)bs*SL*DHD;
  #pragma unroll
  for (int p=0;p<8;p++){
    int row = p*16 + (tid>>4); int ch = tid&15;
    {
      int orig = idxq[row];
      uint2 u = *(const uint2*)(qbb + (size_t)orig*DHD + ch*4);
      *(uint2*)(qs + sw128(row, ch*8)) = u;
    }
    {
      int orig = idxk[row];
      uint2 u = *(const uint2*)(kbb + (size_t)orig*DHD + ch*4);
      *(uint2*)(ks_ + sw128(row, ch*8)) = u;
    }
    {
      int orig = idxk[row];
      ushort4 vv = *(const ushort4*)(vb + (size_t)orig*DHD + ch*4);
      unsigned short arr[4] = {vv.x, vv.y, vv.z, vv.w};
      #pragma unroll
      for (int ii=0;ii<4;ii++){
        int d = ch*4+ii;
        *(unsigned short*)(vt + sw256(d, row*2)) = arr[ii];
      }
    }
  }
  __syncthreads();

  // S = q_s @ k_s^T
  f32x4 sc[2][8] = {};
  #pragma unroll
  for (int ks=0;ks<2;ks++){
    int cb = ks*64 + ((l>>4)<<4);
    short8 aq[2];
    aq[0] = *(const short8*)(qs + sw128(w*32 +      (l&15), cb));
    aq[1] = *(const short8*)(qs + sw128(w*32 + 16 + (l&15), cb));
    #pragma unroll
    for (int nj=0;nj<8;nj++){
      short8 bk = *(const short8*)(ks_ + sw128(nj*16+(l&15), cb));
      sc[0][nj] = __builtin_amdgcn_mfma_f32_16x16x32_bf16(aq[0], bk, sc[0][nj],0,0,0);
      sc[1][nj] = __builtin_amdgcn_mfma_f32_16x16x32_bf16(aq[1], bk, sc[1][nj],0,0,0);
    }
  }
  __syncthreads();

  // row-wise softmax (16-lane groups hold a row)
  #pragma unroll
  for (int mi=0;mi<2;mi++)
  #pragma unroll
  for (int rr=0;rr<4;rr++){
    float mx = -3.0e38f;
    #pragma unroll
    for (int nj=0;nj<8;nj++) mx = fmaxf(mx, sc[mi][nj][rr]);
    #pragma unroll
    for (int off=1; off<16; off<<=1) mx = fmaxf(mx, __shfl_xor(mx, off));
    float s = 0.f;
    #pragma unroll
    for (int nj=0;nj<8;nj++){ float p_ = expf(sc[mi][nj][rr]-mx); sc[mi][nj][rr]=p_; s += p_; }
    #pragma unroll
    for (int off=1; off<16; off<<=1) s += __shfl_xor(s, off);
    float inv = 1.0f/s;
    int row = w*32 + mi*16 + (l>>4)*4 + rr;
    #pragma unroll
    for (int nj=0;nj<8;nj++){
      int col = nj*16 + (l&15);
      *(unsigned short*)(P + sw256(row, col*2)) = f2bf(sc[mi][nj][rr]*inv);
    }
    if ((l&15)==0){
      int orig = idxq[row];
      lseh[rowbase + orig] = mx + logf(s);
    }
  }
  __syncthreads();

  // O = P @ V
  f32x4 o[2][4] = {};
  #pragma unroll
  for (int ks=0;ks<4;ks++){
    int cb = ks*64 + ((l>>4)<<4);
    short8 pa[2];
    pa[0] = *(const short8*)(P + sw256(w*32 +      (l&15), cb));
    pa[1] = *(const short8*)(P + sw256(w*32 + 16 + (l&15), cb));
    #pragma unroll
    for (int nd=0;nd<4;nd++){
      short8 bv = *(const short8*)(vt + sw256(nd*16+(l&15), cb));
      o[0][nd] = __builtin_amdgcn_mfma_f32_16x16x32_bf16(pa[0], bv, o[0][nd],0,0,0);
      o[1][nd] = __builtin_amdgcn_mfma_f32_16x16x32_bf16(pa[1], bv, o[1][nd],0,0,0);
    }
  }
  #pragma unroll
  for (int mi=0;mi<2;mi++)
  #pragma unroll
  for (int nd=0;nd<4;nd++)
  #pragma unroll
  for (int rr=0;rr<4;rr++){
    int row = w*32 + mi*16 + (l>>4)*4 + rr;
    int orig = idxq[row];
    oh[(rowbase + orig)*DHD + nd*16 + (l&15)] = f2bf(o[mi][nd][rr]);
  }
}

// ---------------- merge hash rounds ----------------
__global__ __launch_bounds__(256) void merge_kernel(const unsigned short* __restrict__ oh,
    const float* __restrict__ lseh, unsigned short* __restrict__ attnb){
  int idx = blockIdx.x*256 + threadIdx.x;
  int d = idx&63; int pos = idx>>6; int ll = pos & (SL-1); int bs = pos >> 11;
  float l0 = lseh[0*NPOS+pos], l1 = lseh[1*NPOS+pos], l2 = lseh[2*NPOS+pos], l3 = lseh[3*NPOS+pos];
  float mx = fmaxf(fmaxf(l0,l1),fmaxf(l2,l3));
  float w0 = expf(l0-mx), w1 = expf(l1-mx), w2 = expf(l2-mx), w3 = expf(l3-mx);
  float inv = 1.0f/(w0+w1+w2+w3);
  float acc = (w0*bf2f(oh[((size_t)0*NPOS+pos)*DHD+d]) +
               w1*bf2f(oh[((size_t)1*NPOS+pos)*DHD+d]) +
               w2*bf2f(oh[((size_t)2*NPOS+pos)*DHD+d]) +
               w3*bf2f(oh[((size_t)3*NPOS+pos)*DHD+d]))*inv;
  int b = bs/NHD, hh = bs%NHD;
  attnb[((size_t)(b*SL)+ll)*EM + hh*DHD + d] = f2bf(acc);
}

// ---------------- generic bf16 NT GEMM, templated tile-N ----------------
// EPI 0: outf = acc + bias + res (fp32).  EPI 1: outb = bf16(gelu(acc + bias)).
template<int EPI, int BN>
__global__ __launch_bounds__(256) void gemm_bf16(const unsigned short* __restrict__ A,
    const unsigned short* __restrict__ Bw, const float* __restrict__ bias,
    const float* __restrict__ res, float* __restrict__ outf, unsigned short* __restrict__ outb,
    int M, int N, int K){
  constexpr int NJ = BN/32;
  __shared__ __align__(16) char smem[16384 + BN*128];
  char* sA = smem; char* sB = smem + 16384;
  const int tid=threadIdx.x, l=tid&63, w=tid>>6, wm=w>>1, wn=w&1;
  const int m0 = blockIdx.x*128, n0 = blockIdx.y*BN;
  const int srow = l>>3, scol = ((l&7)^srow)<<3;
  f32x4 acc[4][NJ] = {};
  const unsigned short* pA = A  + (size_t)(m0 + w*32 + srow)*K + scol;
  const unsigned short* pB = Bw + (size_t)(n0 + w*(BN/4) + srow)*K + scol;
  for (int k0=0;k0<K;k0+=64){
    __syncthreads();
    #pragma unroll
    for (int c=0;c<4;c++)
      gll16(pA + k0 + c*8*K, sA + w*4096 + c*1024);
    #pragma unroll
    for (int c=0;c<BN/32;c++)
      gll16(pB + k0 + c*8*K, sB + w*(BN*32) + c*1024);
    __syncthreads();
    #pragma unroll
    for (int ks=0;ks<2;ks++){
      int cb = ks*64 + ((l>>4)<<4);
      short8 af[4], bfr[NJ];
      #pragma unroll
      for (int i=0;i<4;i++)
        af[i]  = *(const short8*)(sA + sw128(wm*64+i*16+(l&15), cb));
      #pragma unroll
      for (int j=0;j<NJ;j++)
        bfr[j] = *(const short8*)(sB + sw128(wn*(BN/2)+j*16+(l&15), cb));
      #pragma unroll
      for (int i=0;i<4;i++)
      #pragma unroll
      for (int j=0;j<NJ;j++)
        acc[i][j] = __builtin_amdgcn_mfma_f32_16x16x32_bf16(af[i], bfr[j], acc[i][j],0,0,0);
    }
  }
  #pragma unroll
  for (int i=0;i<4;i++)
  #pragma unroll
  for (int j=0;j<NJ;j++)
  #pragma unroll
  for (int rr=0;rr<4;rr++){
    int gm = m0 + wm*64 + i*16 + (l>>4)*4 + rr;
    int gn = n0 + wn*(BN/2) + j*16 + (l&15);
    float v = acc[i][j][rr] + bias[gn];
    size_t oidx = (size_t)gm*N + gn;
    if (EPI==0) outf[oidx] = v + res[oidx];
    else { float ge = 0.5f*v*(1.0f + erff(v*0.70710678118654752f)); outb[oidx] = f2bf(ge); }
  }
}

extern "C" void kernel_launch(void* const* d_in, const int* in_sizes, int n_in,
                              void* d_out, int out_size, void* d_ws, size_t ws_size,
                              hipStream_t stream){
  const float* x    = (const float*)d_in[0];
  const float* ln1g = (const float*)d_in[1];
  const float* ln1b = (const float*)d_in[2];
  const float* wqkv = (const float*)d_in[3];
  const float* bqkv = (const float*)d_in[4];
  const float* wout = (const float*)d_in[5];
  const float* bout = (const float*)d_in[6];
  const float* ln2g = (const float*)d_in[7];
  const float* ln2b = (const float*)d_in[8];
  const float* w1   = (const float*)d_in[9];
  const float* b1   = (const float*)d_in[10];
  const float* w2   = (const float*)d_in[11];
  const float* b2   = (const float*)d_in[12];
  const float* alpha= (const float*)d_in[13];
  const float* beta = (const float*)d_in[14];
  float* out = (float*)d_out;

  char* ws = (char*)d_ws;
  size_t off = 0;
  auto A = [&](size_t n)->char*{ char* p = ws+off; off += (n+255)&~(size_t)255; return p; };
  _Float16* h_hi = (_Float16*)A(12582912);
  _Float16* h_lo = (_Float16*)A(12582912);
  _Float16* wq_h = (_Float16*)A(3538944);
  _Float16* wq_l = (_Float16*)A(3538944);
  unsigned short* wo_b = (unsigned short*)A(1179648);
  unsigned short* w1_b = (unsigned short*)A(4718592);
  unsigned short* w2_b = (unsigned short*)A(4718592);
  unsigned short* qb16 = (unsigned short*)A(12582912);
  unsigned short* kb16 = (unsigned short*)A(12582912);
  unsigned short* vbuf = (unsigned short*)A(12582912);
  float* qsq = (float*)A(393216);
  float* ksq = (float*)A(393216);
  unsigned* scal = (unsigned*)A(256);
  float* hqp = (float*)A(1572864);
  float* hkp = (float*)A(1572864);
  float* hq = (float*)A(1572864);
  float* hk = (float*)A(1572864);
  int* qpos = (int*)A(1572864);
  int* kpos = (int*)A(1572864);
  unsigned short* oh = (unsigned short*)A(50331648);
  float* lseh = (float*)A(1572864);
  unsigned short* ub = (unsigned short*)A(50331648);
  // aliases (lifetime-disjoint)
  unsigned short* attnb = vbuf;                 // v dead after attn_kernel
  float* x2 = (float*)oh;                       // oh dead after merge_kernel
  unsigned short* yb = (unsigned short*)h_hi;   // h dead after qkv_gemm

  hipMemsetAsync(scal, 0, 8, stream);
  { int n = 2304*768; wsplit_kernel<<<(n+255)/256, 256, 0, stream>>>(wqkv, wq_h, wq_l, n); }
  { int n = 768*768;  tobf_kernel<<<(n+255)/256, 256, 0, stream>>>(wout, wo_b, n); }
  { int n = 3072*768; tobf_kernel<<<(n+255)/256, 256, 0, stream>>>(w1, w1_b, n); }
  { int n = 768*3072; tobf_kernel<<<(n+255)/256, 256, 0, stream>>>(w2, w2_b, n); }
  ln_kernel<0><<<MLROWS, 256, 0, stream>>>(x, ln1g, ln1b, h_hi, h_lo, nullptr);
  qkv_gemm<<<dim3(64,18), 256, 0, stream>>>(h_hi, h_lo, wq_h, wq_l, bqkv, alpha,
                                            qb16, kb16, vbuf, qsq, ksq, scal, hqp, hkp);
  hashfin_kernel<<<768, 256, 0, stream>>>(qsq, ksq, scal, hqp, hkp, alpha, beta, hq, hk);
  sort_kernel<<<384, 1024, 0, stream>>>(hq, hk, qpos, kpos);
  attn_kernel<<<3072, 256, 0, stream>>>(qb16, kb16, vbuf, qpos, kpos, oh, lseh);
  merge_kernel<<<24576, 256, 0, stream>>>(oh, lseh, attnb);
  gemm_bf16<0,64><<<dim3(64,12),  256, 0, stream>>>(attnb, wo_b, bout, x,  x2,  nullptr, MLROWS, 768, 768);
  ln_kernel<1><<<MLROWS, 256, 0, stream>>>(x2, ln2g, ln2b, nullptr, nullptr, yb);
  gemm_bf16<1,128><<<dim3(64,24), 256, 0, stream>>>(yb, w1_b, b1, nullptr, nullptr, ub, MLROWS, 3072, 768);
  gemm_bf16<0,64><<<dim3(64,12),  256, 0, stream>>>(ub, w2_b, b2, x2, out, nullptr, MLROWS, 768, 3072);
}